// Round 1
// 283.182 us; speedup vs baseline: 1.0600x; 1.0600x over previous
//
#include <hip/hip_runtime.h>

#define B_     64
#define DIM_   384
#define RES_   14
#define N_     196
#define HEADS_ 8
#define KD_    32
#define D_     128
#define DH_    1024
#define QK_    256
#define CH_    1536
#define EPS_   1e-5f
#define SCALE_ 0.17677669529663687f   // 32^-0.5

typedef unsigned short u16;
typedef unsigned int u32;
typedef short v8s __attribute__((ext_vector_type(8)));
typedef float v4f __attribute__((ext_vector_type(4)));
typedef u16  v4u __attribute__((ext_vector_type(4)));

static __device__ __forceinline__ u16 f2bf(float f) {
    unsigned int u = __builtin_bit_cast(unsigned int, f);
    u = (u + 0x7fffu + ((u >> 16) & 1u)) >> 16;
    return (u16)u;
}
static __device__ __forceinline__ float bf2f(u16 u) {
    unsigned int x = ((unsigned int)u) << 16;
    return __builtin_bit_cast(float, x);
}
static __device__ __forceinline__ u16 f2h(float f) {
    _Float16 h = (_Float16)f;
    return __builtin_bit_cast(u16, h);
}
static __device__ __forceinline__ float h2f(u16 u) {
    return (float)__builtin_bit_cast(_Float16, u);
}

// workspace layout (u16 element offsets)
// GEMM operand images: [kstep][kquad(4)][row(128)][8] = 4096 elems (8KB)/kstep
#define WBI_OFF  0u          // Wb  image: 12 mtiles x 12 ksteps      (589824)
#define WPI_OFF  589824u     // wp  image: 3 mtiles x 32 ksteps       (393216)
#define QI_OFF   983040u     // qT  [B][8][256][32]                   (4194304)
#define KI_OFF   5177344u    // kT  [B][8][256][32]                   (4194304)
#define VI_OFF   9371648u    // v   image: [B][8] x 7 ksteps          (14680064)
#define PBI_OFF  24051712u   // (unused after attn+AV fusion)
#define VLOC_U16 53411840u   // vlocI in aoI image layout             (16777216)
#define TAIL_OFF 79101952u   // union: xI (6291456) / aoI (16777216)
#define TB_OFF   98770944u   // BN tables fp32[5888]
#define ABT_OFF  98782720u   // abT1 [196][8] fp32 (th1-folded bias)
#define BIASE_OFF 98785920u  // biasE [196][8][196] fp32 (614656 u16)

// ---------------------------------------------------------------------------
// barrier-free direct-from-global 128x128 MFMA core. Operands pre-packed in
// fragment order; 2-deep software pipeline, NO LDS, NO __syncthreads.
// ---------------------------------------------------------------------------
template<int KSTEPS>
static __device__ __forceinline__ void gemm_direct(
    const u16* __restrict__ Ag, const u16* __restrict__ Bg,
    v4f acc[4][4], int tid)
{
    const int lane = tid & 63, w = tid >> 6;
    const int wm = (w & 1) * 64, wn = (w >> 1) * 64;
    const int quad = lane >> 4, l16 = lane & 15;
    const u16* pa = Ag + quad * 1024 + (wm + l16) * 8;
    const u16* pb = Bg + quad * 1024 + (wn + l16) * 8;
    v8s a[2][4], b[2][4];
    #pragma unroll
    for (int i = 0; i < 4; i++) {
        a[0][i] = *(const v8s*)(pa + i * 128);
        b[0][i] = *(const v8s*)(pb + i * 128);
    }
    #pragma unroll
    for (int ks = 0; ks < KSTEPS; ks++) {
        const int cur = ks & 1, nxt = cur ^ 1;
        if (ks + 1 < KSTEPS) {
            const u16* qa = pa + (size_t)(ks + 1) * 4096;
            const u16* qb = pb + (size_t)(ks + 1) * 4096;
            #pragma unroll
            for (int i = 0; i < 4; i++) {
                a[nxt][i] = *(const v8s*)(qa + i * 128);
                b[nxt][i] = *(const v8s*)(qb + i * 128);
            }
        }
        #pragma unroll
        for (int i = 0; i < 4; i++)
            #pragma unroll
            for (int j = 0; j < 4; j++)
                acc[i][j] = __builtin_amdgcn_mfma_f32_16x16x32_bf16(a[cur][i], b[cur][j], acc[i][j], 0, 0, 0);
    }
}

// ---------------------------------------------------------------------------
// pack weights into tile images + abT1 (th1-folded bias) + BN tables
// ---------------------------------------------------------------------------
__global__ __launch_bounds__(256) void k_castW(
    const float* __restrict__ wq, const float* __restrict__ wk,
    const float* __restrict__ wv, const float* __restrict__ wp,
    const float* __restrict__ ab,
    const float* __restrict__ th1w, const float* __restrict__ th1b,
    const float* __restrict__ bq, const float* __restrict__ bnq,
    const float* __restrict__ bk, const float* __restrict__ bnk,
    const float* __restrict__ bv, const float* __restrict__ bnv,
    const float* __restrict__ bp, const float* __restrict__ bnp,
    const float* __restrict__ bvl, const float* __restrict__ bnvl,
    u16* __restrict__ WbI, u16* __restrict__ WpI,
    float* __restrict__ abT1, float* __restrict__ TB)
{
    int i = blockIdx.x * 256 + threadIdx.x;
    if (i < 589824) {           // qkv weight image
        int mt = i / 49152, rem = i % 49152;
        int ks = rem >> 12, r2 = rem & 4095;
        int q = r2 >> 10, row = (r2 >> 3) & 127, e = r2 & 7;
        int c = mt * 128 + row, k = ks * 32 + q * 8 + e;
        float v = (c < 256) ? wq[c * 384 + k]
                : (c < 512) ? wk[(c - 256) * 384 + k]
                            : wv[(size_t)(c - 512) * 384 + k];
        WbI[i] = f2bf(v);
    } else if (i < 983040) {    // proj weight image
        int j = i - 589824;
        int mt = j >> 17, rem = j & 131071;
        int ks = rem >> 12, r2 = rem & 4095;
        int q = r2 >> 10, row = (r2 >> 3) & 127, e = r2 & 7;
        int p = mt * 128 + row, k = ks * 32 + q * 8 + e;
        WpI[j] = f2bf(wp[(size_t)p * 1024 + k]);
    } else if (i < 984608) {    // abT1[idx][o] = th1b[o] + sum_h th1w[o][h]*ab[h][idx]
        int j = i - 983040;
        int idx = j >> 3, o = j & 7;
        float a = th1b[o];
        #pragma unroll
        for (int h = 0; h < 8; h++) a += th1w[o * 8 + h] * ab[h * N_ + idx];
        abT1[j] = a;
    } else if (i < 987552) {    // BN tables
        int j = i - 984608;
        if (j < 256) {
            int c = j;
            float s = bnq[c] * rsqrtf(bnq[768 + c] + EPS_);
            float t = (bq[c] - bnq[512 + c]) * s + bnq[256 + c];
            TB[c] = s * SCALE_; TB[256 + c] = t * SCALE_;
        } else if (j < 512) {
            int c = j - 256;
            float s = bnk[c] * rsqrtf(bnk[768 + c] + EPS_);
            float t = (bk[c] - bnk[512 + c]) * s + bnk[256 + c];
            TB[512 + c] = s; TB[768 + c] = t;
        } else if (j < 1536) {
            int c = j - 512;
            float s = bnv[c] * rsqrtf(bnv[3072 + c] + EPS_);
            float t = (bv[c] - bnv[2048 + c]) * s + bnv[1024 + c];
            TB[1024 + c] = s; TB[2048 + c] = t;
        } else if (j < 1920) {
            int c = j - 1536;
            float s = bnp[c] * rsqrtf(bnp[1152 + c] + EPS_);
            float t = (bp[c] - bnp[768 + c]) * s + bnp[384 + c];
            TB[3072 + c] = s; TB[3456 + c] = t;
        } else {
            int c = j - 1920;
            float s = bnvl[c] * rsqrtf(bnvl[3072 + c] + EPS_);
            float t = (bvl[c] - bnvl[2048 + c]) * s + bnvl[1024 + c];
            TB[3840 + c] = s; TB[4864 + c] = t;
        }
    }
}

// ---------------------------------------------------------------------------
// expand bias: biasE[n][o][m] = abT1[bidx[n][m]][o] - 5  (batch-independent)
// ---------------------------------------------------------------------------
__global__ __launch_bounds__(256) void k_bias(
    const float* __restrict__ abT1, const int* __restrict__ bidx,
    float* __restrict__ biasE)
{
    int i = blockIdx.x * 256 + threadIdx.x;
    if (i >= N_ * 8 * N_) return;
    int m = i % N_;
    int t = i / N_;
    int o = t & 7;
    int n = t >> 3;
    biasE[i] = abT1[bidx[n * N_ + m] * 8 + o] - 5.f;
}

// ---------------------------------------------------------------------------
// x [B,384,196] fp32 -> xI image [B][nt2][12 ksteps][4096] bf16 (n>=196 zero)
// ---------------------------------------------------------------------------
__global__ __launch_bounds__(256) void k_castX(
    const float* __restrict__ x, u16* __restrict__ xI)
{
    __shared__ float T[64][65];
    const int tid = threadIdx.x;
    const int n0 = blockIdx.x * 64;
    const int k0 = blockIdx.y * 64;
    const int b  = blockIdx.z;
    const int c = tid & 63, r4 = tid >> 6;
    #pragma unroll
    for (int i = 0; i < 16; i++) {
        int kr = i * 4 + r4;
        int gn = n0 + c;
        T[kr][c] = (gn < N_) ? x[((size_t)b * DIM_ + k0 + kr) * N_ + gn] : 0.f;
    }
    __syncthreads();
    #pragma unroll
    for (int it = 0; it < 16; it++) {
        int j = it * 256 + tid;
        int kk = j & 63, nn = j >> 6;
        int k = k0 + kk, n = n0 + nn;
        xI[(size_t)b * 98304 + (n >> 7) * 49152 + (k >> 5) * 4096
           + ((k >> 3) & 3) * 1024 + (n & 127) * 8 + (k & 7)] = f2bf(T[kk][nn]);
    }
}

// ---------------------------------------------------------------------------
// K1: QKV GEMM (direct core). qI/kI [b][h][256][32] bf16 (q pre-scaled),
// vI image per (b,o), 7 ksteps (n>=196 zero).
// XCD swizzle: 1536 blocks = 8 XCDs x (8 b x 24 tiles) so each XCD's L2
// holds one b-range's xI slices (kills the ~8x cross-XCD xI re-fetch).
// ---------------------------------------------------------------------------
__global__ __launch_bounds__(256) void k_qkv(
    const u16* __restrict__ WbI, const u16* __restrict__ xI,
    const float* __restrict__ TB,
    u16* __restrict__ qI, u16* __restrict__ kI, u16* __restrict__ vI)
{
    const int tid = threadIdx.x;
    const int L = blockIdx.x + 2 * (blockIdx.y + 12 * blockIdx.z);
    const int idx = L >> 3;                 // 0..191
    const int b  = (L & 7) * 8 + idx / 24;  // contiguous b-chunk per XCD
    const int r  = idx % 24;
    const int mt = r >> 1, nt = r & 1;
    v4f acc[4][4] = {};
    gemm_direct<12>(WbI + (size_t)mt * 49152,
                    xI + ((size_t)b * 2 + nt) * 49152, acc, tid);

    const int lane = tid & 63, w = tid >> 6;
    const int wm = (w & 1) * 64, wn = (w >> 1) * 64;
    const int quad = lane >> 4, l16 = lane & 15;
    #pragma unroll
    for (int i = 0; i < 4; i++) {
        #pragma unroll
        for (int j = 0; j < 4; j++) {
            int gc = mt * 128 + wm + i * 16 + quad * 4;  // global channel base
            int n  = nt * 128 + wn + j * 16 + l16;       // token (0..255)
            v4f v = acc[i][j];
            if (gc < 256) {            // q
                v4f s = *(const v4f*)&TB[gc];
                v4f t = *(const v4f*)&TB[256 + gc];
                v4u u;
                #pragma unroll
                for (int r2 = 0; r2 < 4; r2++) u[r2] = f2bf(v[r2] * s[r2] + t[r2]);
                *(v4u*)&qI[((size_t)(b * 8 + (gc >> 5)) * 256 + n) * 32 + (gc & 31)] = u;
            } else if (gc < 512) {     // k
                int c = gc - 256;
                v4f s = *(const v4f*)&TB[512 + c];
                v4f t = *(const v4f*)&TB[768 + c];
                v4u u;
                #pragma unroll
                for (int r2 = 0; r2 < 4; r2++) u[r2] = f2bf(v[r2] * s[r2] + t[r2]);
                *(v4u*)&kI[((size_t)(b * 8 + (c >> 5)) * 256 + n) * 32 + (c & 31)] = u;
            } else {                   // v -> image (row = e, col = n as k-dim)
                int c = gc - 512;      // 0..1023
                if (n < 224) {
                    int o = c >> 7, e = c & 127;
                    u16* base = vI + ((size_t)(b * 8 + o) * 7 + (n >> 5)) * 4096
                                + ((n >> 3) & 3) * 1024 + (n & 7);
                    #pragma unroll
                    for (int r2 = 0; r2 < 4; r2++) {
                        u16 outv = 0;
                        if (n < N_) outv = f2bf(v[r2] * TB[1024 + c + r2] + TB[2048 + c + r2]);
                        base[(e + r2) * 8] = outv;
                    }
                }
            }
        }
    }
}

// ---------------------------------------------------------------------------
// K2: depthwise 3x3 conv. Block = 64 channels of one (b,o).
// Writes vlocI in the aoI image layout so the fused AV epilogue reads vectorized.
// ---------------------------------------------------------------------------
__global__ __launch_bounds__(256) void k_dwconv(
    const u16* __restrict__ vI, const float* __restrict__ wvl,
    const float* __restrict__ TB, u16* __restrict__ vlocI)
{
    __shared__ u16 V[64 * 230];             // 29440 B
    const int tid = threadIdx.x;
    const int sub = blockIdx.x;             // 0..15: o = sub>>1, half = sub&1
    const int b   = blockIdx.y;
    const int o   = sub >> 1;
    const int e0  = (sub & 1) * 64;
    const u16* img = vI + (size_t)(b * 8 + o) * 28672;

    {
        const int quad = tid >> 6, l = tid & 63;
        #pragma unroll
        for (int i = 0; i < 7; i++) {
            v8s u = *(const v8s*)&img[i * 4096 + quad * 1024 + (e0 + l) * 8];
            const u32* ui = (const u32*)&u;
            int m0 = i * 32 + quad * 8;
            u32* dst = (u32*)&V[l * 230 + m0];
            #pragma unroll
            for (int c = 0; c < 4; c++) dst[c] = ui[c];
        }
    }
    __syncthreads();

    const int e = tid & 63, j = tid >> 6;
    const int cg = sub * 64 + e;
    const int y0 = j * 4;
    const int ny = (j == 3) ? 2 : 4;
    float wgt[9];
    #pragma unroll
    for (int k = 0; k < 9; k++) wgt[k] = wvl[cg * 9 + k];
    const float sc = TB[3840 + cg], sh = TB[4864 + cg];
    u32 po[4][7];

    for (int yi = 0; yi < ny; yi++) {
        int y = y0 + yi;
        float a[3][16];
        #pragma unroll
        for (int dy = 0; dy < 3; dy++) {
            int yy = y + dy - 1;
            a[dy][0] = 0.f; a[dy][15] = 0.f;
            if (yy < 0 || yy > 13) {
                #pragma unroll
                for (int x = 1; x < 15; x++) a[dy][x] = 0.f;
            } else {
                const u16* rp = &V[e * 230 + yy * 14];
                #pragma unroll
                for (int c4 = 0; c4 < 7; c4++) {
                    u32 u = *(const u32*)&rp[c4 * 2];
                    a[dy][1 + 2 * c4] = bf2f((u16)(u & 0xffffu));
                    a[dy][2 + 2 * c4] = bf2f((u16)(u >> 16));
                }
            }
        }
        #pragma unroll
        for (int xp = 0; xp < 7; xp++) {
            u32 pk = 0;
            #pragma unroll
            for (int half = 0; half < 2; half++) {
                int x = 2 * xp + half;
                float s = 0.f;
                #pragma unroll
                for (int dy = 0; dy < 3; dy++)
                    #pragma unroll
                    for (int kx = 0; kx < 3; kx++)
                        s += wgt[dy * 3 + kx] * a[dy][x + kx];
                u16 bv = f2bf(s * sc + sh);
                pk |= ((u32)bv) << (16 * half);
            }
            po[yi][xp] = pk;
        }
    }
    __syncthreads();

    for (int yi = 0; yi < ny; yi++) {
        u32* dst = (u32*)&V[e * 196 + (y0 + yi) * 14];
        #pragma unroll
        for (int xp = 0; xp < 7; xp++) dst[xp] = po[yi][xp];
    }
    __syncthreads();

    for (int it = 0; it < 7; it++) {
        int idx = it * 256 + tid;
        if (idx < 1568) {
            int g = idx / 196, n = idx - g * 196;
            v4u lo, hi;
            #pragma unroll
            for (int r = 0; r < 4; r++) lo[r] = V[(g * 8 + r) * 196 + n];
            #pragma unroll
            for (int r = 0; r < 4; r++) hi[r] = V[(g * 8 + 4 + r) * 196 + n];
            u16* dst = vlocI + ((size_t)(b * 2 + (n >> 7)) * 32 + sub * 2 + (g >> 2)) * 4096
                     + (g & 3) * 1024 + (n & 127) * 8;
            *(v4u*)dst = lo;
            *(v4u*)(dst + 4) = hi;
        }
    }
}

// ---------------------------------------------------------------------------
// K3: FUSED attention + AV + vloc + relu -> aoI. Block = (qtile8, b).
// P never touches HBM: after phase B3 it lives in Sl (bf16, fragment-ready),
// phase C streams V fragments straight from the vI image (L2-resident via
// the XCD swizzle) and MFMAs against Sl rows.
// XCD swizzle: 1600 blocks = 8 XCDs x (8 b x 25 qt).
// ---------------------------------------------------------------------------
__global__ __launch_bounds__(256) void k_attn_av(
    const u16* __restrict__ qI, const u16* __restrict__ kI,
    const u16* __restrict__ vI,
    const float* __restrict__ th1w,
    const float* __restrict__ th2w, const float* __restrict__ th2b,
    const float* __restrict__ biasE,
    const u16* __restrict__ vlocI, u16* __restrict__ aoI)
{
    __shared__ u16 Sl[8 * 8 * 228];   // [h][q][m] = 29184 B
    __shared__ float red[64][4];
    __shared__ float invS[64];        // [h*8+q]
    const int tid = threadIdx.x;
    const int w = tid >> 6, lane = tid & 63;
    const int quad = lane >> 4, l16 = lane & 15;
    const int L = blockIdx.x + 25 * blockIdx.y;
    const int idx = L >> 3;                 // 0..199
    const int b  = (L & 7) * 8 + idx / 25;  // contiguous b-chunk per XCD
    const int qt = idx % 25;                // 0..24
    const int n0 = qt * 8;

    // phase A: wave w -> heads 2w, 2w+1; unrolled so kI loads pipeline
    #pragma unroll
    for (int hh = 0; hh < 2; hh++) {
        int h = w * 2 + hh;
        const u16* qb = qI + (size_t)(b * 8 + h) * 8192;
        const u16* kb = kI + (size_t)(b * 8 + h) * 8192;
        v8s a = *(const v8s*)&qb[(n0 + l16) * 32 + quad * 8];
        #pragma unroll
        for (int mt = 0; mt < 13; mt++) {
            v8s bfr = *(const v8s*)&kb[(mt * 16 + l16) * 32 + quad * 8];
            v4f acc = {};
            acc = __builtin_amdgcn_mfma_f32_16x16x32_bf16(a, bfr, acc, 0, 0, 0);
            if (quad < 2) {
                #pragma unroll
                for (int r = 0; r < 4; r++) {
                    int q = quad * 4 + r;
                    Sl[(h * 8 + q) * 228 + mt * 16 + l16] = f2h(acc[r]);
                }
            }
        }
    }
    __syncthreads();

    // phase B1: thread owns column m; coalesced biasE reads; exp in place fp16
    const int m = tid;
    const bool mact = (m < N_);
    for (int q = 0; q < 8; q++) {
        int n = n0 + q;
        if (mact && n < N_) {
            const float* bE = biasE + (size_t)n * 1568 + m;
            float S[8];
            #pragma unroll
            for (int h = 0; h < 8; h++) S[h] = h2f(Sl[(h * 8 + q) * 228 + m]);
            float E[8];
            #pragma unroll
            for (int o = 0; o < 8; o++) {
                float a = bE[o * 196];
                #pragma unroll
                for (int h = 0; h < 8; h++) a += th1w[o * 8 + h] * S[h];
                E[o] = __expf(a);
            }
            #pragma unroll
            for (int o = 0; o < 8; o++)
                Sl[(o * 8 + q) * 228 + m] = f2h(E[o]);
        }
    }
    __syncthreads();

    // phase B2: 64 rows x 4 threads; vectorized u32 LDS reads
    {
        int r = tid >> 2, quarter = tid & 3;
        int mstart = quarter * 48;
        int cnt = (quarter == 3) ? 26 : 24;
        const u16* rowp = &Sl[r * 228 + mstart];
        float s = 0.f;
        for (int i = 0; i < cnt; i++) {
            u32 u = *(const u32*)&rowp[i * 2];
            s += h2f((u16)(u & 0xffffu)) + h2f((u16)(u >> 16));
        }
        red[r][quarter] = s;
    }
    __syncthreads();
    if (tid < 64)
        invS[tid] = 1.f / (red[tid][0] + red[tid][1] + red[tid][2] + red[tid][3]);
    __syncthreads();

    // phase B3: scale + TH2 in place (bf16)
    for (int q = 0; q < 8; q++) {
        bool valid = mact && (n0 + q < N_);
        float p[8];
        if (valid) {
            float sc[8];
            #pragma unroll
            for (int h = 0; h < 8; h++)
                sc[h] = h2f(Sl[(h * 8 + q) * 228 + m]) * invS[h * 8 + q];
            #pragma unroll
            for (int o = 0; o < 8; o++) {
                float v = th2b[o];
                #pragma unroll
                for (int h = 0; h < 8; h++) v += th2w[o * 8 + h] * sc[h];
                p[o] = v;
            }
        }
        if (m < 224) {
            #pragma unroll
            for (int o = 0; o < 8; o++)
                Sl[(o * 8 + q) * 228 + m] = valid ? f2bf(p[o]) : (u16)0;
        }
    }
    __syncthreads();

    // phase C: AV. Wave w handles o = 2w, 2w+1.
    // A = vI fragments (global, image order); B = Sl rows (P, bf16).
    // B rows l16>=8 duplicate rows 0..7 -> output cols 8..15 discarded.
    {
        const int half_ = n0 >> 7;
        const int row0 = n0 & 127;
        const int n = n0 + l16;
        const bool act = (l16 < 8) && (n < N_);
        for (int oo = 0; oo < 2; oo++) {
            const int o = w * 2 + oo;
            const u16* vb = vI + (size_t)(b * 8 + o) * 28672;
            const u16* prow = &Sl[(o * 8 + (l16 & 7)) * 228];
            #pragma unroll
            for (int eh = 0; eh < 2; eh++) {       // 4 e-tiles per half
                v4f acc[4] = {};
                v8s a[2][4];
                const u16* ab0 = vb + quad * 1024 + (eh * 64 + l16) * 8;
                #pragma unroll
                for (int e = 0; e < 4; e++) a[0][e] = *(const v8s*)(ab0 + e * 128);
                #pragma unroll
                for (int ks = 0; ks < 7; ks++) {
                    const int cur = ks & 1, nxt = cur ^ 1;
                    if (ks < 6) {
                        const u16* an = ab0 + (size_t)(ks + 1) * 4096;
                        #pragma unroll
                        for (int e = 0; e < 4; e++) a[nxt][e] = *(const v8s*)(an + e * 128);
                    }
                    v8s bfr = *(const v8s*)&prow[ks * 32 + quad * 8];
                    #pragma unroll
                    for (int e = 0; e < 4; e++)
                        acc[e] = __builtin_amdgcn_mfma_f32_16x16x32_bf16(a[cur][e], bfr, acc[e], 0, 0, 0);
                }
                if (act) {
                    #pragma unroll
                    for (int e = 0; e < 4; e++) {
                        const int c0 = o * 128 + (eh * 4 + e) * 16 + quad * 4;
                        const size_t ioff = ((size_t)(b * 2 + half_) * 32 + (c0 >> 5)) * 4096
                                          + ((c0 >> 3) & 3) * 1024 + (size_t)(row0 + l16) * 8 + (c0 & 7);
                        v4u lv = *(const v4u*)&vlocI[ioff];
                        v4u u;
                        #pragma unroll
                        for (int r = 0; r < 4; r++)
                            u[r] = f2bf(fmaxf(acc[e][r] + bf2f(lv[r]), 0.f));
                        *(v4u*)&aoI[ioff] = u;
                    }
                }
            }
        }
    }
}

// ---------------------------------------------------------------------------
// K6: projection GEMM (direct core, K=1024) + BN -> out fp32
// XCD swizzle: 384 blocks = 8 XCDs x (8 b x 6 tiles).
// ---------------------------------------------------------------------------
__global__ __launch_bounds__(256) void k_proj(
    const u16* __restrict__ WpI, const u16* __restrict__ aoI,
    const float* __restrict__ TB, float* __restrict__ out)
{
    const int tid = threadIdx.x;
    const int L = blockIdx.x + 2 * (blockIdx.y + 3 * blockIdx.z);
    const int idx = L >> 3;                 // 0..47
    const int b  = (L & 7) * 8 + idx / 6;   // contiguous b-chunk per XCD
    const int r  = idx % 6;
    const int mt = r >> 1, nt = r & 1;
    v4f acc[4][4] = {};
    gemm_direct<32>(WpI + (size_t)mt * 131072,
                    aoI + ((size_t)b * 2 + nt) * 131072, acc, tid);

    const int lane = tid & 63, w = tid >> 6;
    const int wm = (w & 1) * 64, wn = (w >> 1) * 64;
    const int quad = lane >> 4, l16 = lane & 15;
    #pragma unroll
    for (int i = 0; i < 4; i++) {
        #pragma unroll
        for (int j = 0; j < 4; j++) {
            int p0 = mt * 128 + wm + i * 16 + quad * 4;
            int n  = nt * 128 + wn + j * 16 + l16;
            if (n < N_) {
                v4f s = *(const v4f*)&TB[3072 + p0];
                v4f t = *(const v4f*)&TB[3456 + p0];
                #pragma unroll
                for (int r2 = 0; r2 < 4; r2++)
                    out[((size_t)b * DIM_ + p0 + r2) * N_ + n] = acc[i][j][r2] * s[r2] + t[r2];
            }
        }
    }
}

// ---------------------------------------------------------------------------
extern "C" void kernel_launch(void* const* d_in, const int* in_sizes, int n_in,
                              void* d_out, int out_size, void* d_ws, size_t ws_size,
                              hipStream_t stream)
{
    const float* x    = (const float*)d_in[0];
    const float* wq   = (const float*)d_in[1];
    const float* bq   = (const float*)d_in[2];
    const float* bnq  = (const float*)d_in[3];
    const float* wk   = (const float*)d_in[4];
    const float* bk   = (const float*)d_in[5];
    const float* bnk  = (const float*)d_in[6];
    const float* wv   = (const float*)d_in[7];
    const float* bv   = (const float*)d_in[8];
    const float* bnv  = (const float*)d_in[9];
    const float* wvl  = (const float*)d_in[10];
    const float* bvl  = (const float*)d_in[11];
    const float* bnvl = (const float*)d_in[12];
    const float* th1w = (const float*)d_in[13];
    const float* th1b = (const float*)d_in[14];
    const float* th2w = (const float*)d_in[15];
    const float* th2b = (const float*)d_in[16];
    const float* wp   = (const float*)d_in[17];
    const float* bp   = (const float*)d_in[18];
    const float* bnp  = (const float*)d_in[19];
    const float* ab   = (const float*)d_in[20];
    const int*   bidx = (const int*)d_in[21];
    float* out = (float*)d_out;

    u16* wsb  = (u16*)d_ws;
    u16* WbI  = wsb + WBI_OFF;
    u16* WpI  = wsb + WPI_OFF;
    u16* qI   = wsb + QI_OFF;
    u16* kI   = wsb + KI_OFF;
    u16* vI   = wsb + VI_OFF;
    u16* vlocI = wsb + VLOC_U16;
    u16* xI   = wsb + TAIL_OFF;   // aliased: xI -> aoI (disjoint lifetimes)
    u16* aoI  = wsb + TAIL_OFF;
    float* TB    = (float*)(wsb + TB_OFF);
    float* abT1  = (float*)(wsb + ABT_OFF);
    float* biasE = (float*)(wsb + BIASE_OFF);

    k_castW<<<dim3(3859), 256, 0, stream>>>(wq, wk, wv, wp, ab, th1w, th1b,
                                            bq, bnq, bk, bnk, bv, bnv, bp, bnp, bvl, bnvl,
                                            WbI, WpI, abT1, TB);
    k_bias<<<dim3((N_ * 8 * N_ + 255) / 256), 256, 0, stream>>>(abT1, bidx, biasE);
    k_castX<<<dim3(4, 6, B_), 256, 0, stream>>>(x, xI);
    k_qkv<<<dim3(2, 12, B_), 256, 0, stream>>>(WbI, xI, TB, qI, kI, vI);
    k_dwconv<<<dim3(16, B_), 256, 0, stream>>>(vI, wvl, TB, vlocI);
    k_attn_av<<<dim3(25, B_), 256, 0, stream>>>(qI, kI, vI, th1w, th2w, th2b,
                                                biasE, vlocI, aoI);
    k_proj<<<dim3(2, 3, B_), 256, 0, stream>>>(WpI, aoI, TB, out);
}

// Round 2
// 270.090 us; speedup vs baseline: 1.1113x; 1.0485x over previous
//
#include <hip/hip_runtime.h>

#define B_     64
#define DIM_   384
#define RES_   14
#define N_     196
#define HEADS_ 8
#define KD_    32
#define D_     128
#define DH_    1024
#define QK_    256
#define CH_    1536
#define EPS_   1e-5f
#define SCALE_ 0.17677669529663687f   // 32^-0.5

typedef unsigned short u16;
typedef unsigned int u32;
typedef short v8s __attribute__((ext_vector_type(8)));
typedef float v4f __attribute__((ext_vector_type(4)));
typedef u16  v4u __attribute__((ext_vector_type(4)));

static __device__ __forceinline__ u16 f2bf(float f) {
    unsigned int u = __builtin_bit_cast(unsigned int, f);
    u = (u + 0x7fffu + ((u >> 16) & 1u)) >> 16;
    return (u16)u;
}
static __device__ __forceinline__ float bf2f(u16 u) {
    unsigned int x = ((unsigned int)u) << 16;
    return __builtin_bit_cast(float, x);
}
static __device__ __forceinline__ u16 f2h(float f) {
    _Float16 h = (_Float16)f;
    return __builtin_bit_cast(u16, h);
}
static __device__ __forceinline__ float h2f(u16 u) {
    return (float)__builtin_bit_cast(_Float16, u);
}

// workspace layout (u16 element offsets)
// GEMM operand images: [kstep][kquad(4)][row(128)][8] = 4096 elems (8KB)/kstep
#define WBI_OFF  0u          // Wb  image: 12 mtiles x 12 ksteps      (589824)
#define WPI_OFF  589824u     // wp  image: 3 mtiles x 32 ksteps       (393216)
#define QI_OFF   983040u     // qT  [B][8][256][32]                   (4194304)
#define KI_OFF   5177344u    // kT  [B][8][256][32]                   (4194304)
#define VI_OFF   9371648u    // v   image: [B][8] x 7 ksteps          (14680064)
#define VLOC_U16 53411840u   // vlocI in aoI image layout             (16777216)
#define TAIL_OFF 79101952u   // union: xI (6291456) / aoI (16777216)
#define TB_OFF   98770944u   // BN tables fp32[5888]
#define ABT_OFF  98782720u   // abT1 [196][8] fp32 (th1-folded bias)
#define BIASE_OFF 98785920u  // biasE [196][8][196] fp32 (614656 u16)

// ---------------------------------------------------------------------------
// barrier-free direct-from-global 128x128 MFMA core. Operands pre-packed in
// fragment order; 2-deep software pipeline, NO LDS, NO __syncthreads.
// ---------------------------------------------------------------------------
template<int KSTEPS>
static __device__ __forceinline__ void gemm_direct(
    const u16* __restrict__ Ag, const u16* __restrict__ Bg,
    v4f acc[4][4], int tid)
{
    const int lane = tid & 63, w = tid >> 6;
    const int wm = (w & 1) * 64, wn = (w >> 1) * 64;
    const int quad = lane >> 4, l16 = lane & 15;
    const u16* pa = Ag + quad * 1024 + (wm + l16) * 8;
    const u16* pb = Bg + quad * 1024 + (wn + l16) * 8;
    v8s a[2][4], b[2][4];
    #pragma unroll
    for (int i = 0; i < 4; i++) {
        a[0][i] = *(const v8s*)(pa + i * 128);
        b[0][i] = *(const v8s*)(pb + i * 128);
    }
    #pragma unroll
    for (int ks = 0; ks < KSTEPS; ks++) {
        const int cur = ks & 1, nxt = cur ^ 1;
        if (ks + 1 < KSTEPS) {
            const u16* qa = pa + (size_t)(ks + 1) * 4096;
            const u16* qb = pb + (size_t)(ks + 1) * 4096;
            #pragma unroll
            for (int i = 0; i < 4; i++) {
                a[nxt][i] = *(const v8s*)(qa + i * 128);
                b[nxt][i] = *(const v8s*)(qb + i * 128);
            }
        }
        #pragma unroll
        for (int i = 0; i < 4; i++)
            #pragma unroll
            for (int j = 0; j < 4; j++)
                acc[i][j] = __builtin_amdgcn_mfma_f32_16x16x32_bf16(a[cur][i], b[cur][j], acc[i][j], 0, 0, 0);
    }
}

// ---------------------------------------------------------------------------
// pack weights into tile images + abT1 (th1-folded bias) + BN tables
// ---------------------------------------------------------------------------
__global__ __launch_bounds__(256) void k_castW(
    const float* __restrict__ wq, const float* __restrict__ wk,
    const float* __restrict__ wv, const float* __restrict__ wp,
    const float* __restrict__ ab,
    const float* __restrict__ th1w, const float* __restrict__ th1b,
    const float* __restrict__ bq, const float* __restrict__ bnq,
    const float* __restrict__ bk, const float* __restrict__ bnk,
    const float* __restrict__ bv, const float* __restrict__ bnv,
    const float* __restrict__ bp, const float* __restrict__ bnp,
    const float* __restrict__ bvl, const float* __restrict__ bnvl,
    u16* __restrict__ WbI, u16* __restrict__ WpI,
    float* __restrict__ abT1, float* __restrict__ TB)
{
    int i = blockIdx.x * 256 + threadIdx.x;
    if (i < 589824) {           // qkv weight image
        int mt = i / 49152, rem = i % 49152;
        int ks = rem >> 12, r2 = rem & 4095;
        int q = r2 >> 10, row = (r2 >> 3) & 127, e = r2 & 7;
        int c = mt * 128 + row, k = ks * 32 + q * 8 + e;
        float v = (c < 256) ? wq[c * 384 + k]
                : (c < 512) ? wk[(c - 256) * 384 + k]
                            : wv[(size_t)(c - 512) * 384 + k];
        WbI[i] = f2bf(v);
    } else if (i < 983040) {    // proj weight image
        int j = i - 589824;
        int mt = j >> 17, rem = j & 131071;
        int ks = rem >> 12, r2 = rem & 4095;
        int q = r2 >> 10, row = (r2 >> 3) & 127, e = r2 & 7;
        int p = mt * 128 + row, k = ks * 32 + q * 8 + e;
        WpI[j] = f2bf(wp[(size_t)p * 1024 + k]);
    } else if (i < 984608) {    // abT1[idx][o] = th1b[o] + sum_h th1w[o][h]*ab[h][idx]
        int j = i - 983040;
        int idx = j >> 3, o = j & 7;
        float a = th1b[o];
        #pragma unroll
        for (int h = 0; h < 8; h++) a += th1w[o * 8 + h] * ab[h * N_ + idx];
        abT1[j] = a;
    } else if (i < 987552) {    // BN tables
        int j = i - 984608;
        if (j < 256) {
            int c = j;
            float s = bnq[c] * rsqrtf(bnq[768 + c] + EPS_);
            float t = (bq[c] - bnq[512 + c]) * s + bnq[256 + c];
            TB[c] = s * SCALE_; TB[256 + c] = t * SCALE_;
        } else if (j < 512) {
            int c = j - 256;
            float s = bnk[c] * rsqrtf(bnk[768 + c] + EPS_);
            float t = (bk[c] - bnk[512 + c]) * s + bnk[256 + c];
            TB[512 + c] = s; TB[768 + c] = t;
        } else if (j < 1536) {
            int c = j - 512;
            float s = bnv[c] * rsqrtf(bnv[3072 + c] + EPS_);
            float t = (bv[c] - bnv[2048 + c]) * s + bnv[1024 + c];
            TB[1024 + c] = s; TB[2048 + c] = t;
        } else if (j < 1920) {
            int c = j - 1536;
            float s = bnp[c] * rsqrtf(bnp[1152 + c] + EPS_);
            float t = (bp[c] - bnp[768 + c]) * s + bnp[384 + c];
            TB[3072 + c] = s; TB[3456 + c] = t;
        } else {
            int c = j - 1920;
            float s = bnvl[c] * rsqrtf(bnvl[3072 + c] + EPS_);
            float t = (bvl[c] - bnvl[2048 + c]) * s + bnvl[1024 + c];
            TB[3840 + c] = s; TB[4864 + c] = t;
        }
    }
}

// ---------------------------------------------------------------------------
// expand bias: biasE[n][o][m] = abT1[bidx[n][m]][o] - 5  (batch-independent)
// ---------------------------------------------------------------------------
__global__ __launch_bounds__(256) void k_bias(
    const float* __restrict__ abT1, const int* __restrict__ bidx,
    float* __restrict__ biasE)
{
    int i = blockIdx.x * 256 + threadIdx.x;
    if (i >= N_ * 8 * N_) return;
    int m = i % N_;
    int t = i / N_;
    int o = t & 7;
    int n = t >> 3;
    biasE[i] = abT1[bidx[n * N_ + m] * 8 + o] - 5.f;
}

// ---------------------------------------------------------------------------
// x [B,384,196] fp32 -> xI image [B][nt2][12 ksteps][4096] bf16 (n>=196 zero)
// ---------------------------------------------------------------------------
__global__ __launch_bounds__(256) void k_castX(
    const float* __restrict__ x, u16* __restrict__ xI)
{
    __shared__ float T[64][65];
    const int tid = threadIdx.x;
    const int n0 = blockIdx.x * 64;
    const int k0 = blockIdx.y * 64;
    const int b  = blockIdx.z;
    const int c = tid & 63, r4 = tid >> 6;
    #pragma unroll
    for (int i = 0; i < 16; i++) {
        int kr = i * 4 + r4;
        int gn = n0 + c;
        T[kr][c] = (gn < N_) ? x[((size_t)b * DIM_ + k0 + kr) * N_ + gn] : 0.f;
    }
    __syncthreads();
    #pragma unroll
    for (int it = 0; it < 16; it++) {
        int j = it * 256 + tid;
        int kk = j & 63, nn = j >> 6;
        int k = k0 + kk, n = n0 + nn;
        xI[(size_t)b * 98304 + (n >> 7) * 49152 + (k >> 5) * 4096
           + ((k >> 3) & 3) * 1024 + (n & 127) * 8 + (k & 7)] = f2bf(T[kk][nn]);
    }
}

// ---------------------------------------------------------------------------
// K1: QKV GEMM (direct core). qI/kI [b][h][256][32] bf16 (q pre-scaled),
// vI image per (b,o), 7 ksteps (n>=196 zero).
// XCD swizzle: 1536 blocks = 8 XCDs x (8 b x 24 tiles).
// ---------------------------------------------------------------------------
__global__ __launch_bounds__(256) void k_qkv(
    const u16* __restrict__ WbI, const u16* __restrict__ xI,
    const float* __restrict__ TB,
    u16* __restrict__ qI, u16* __restrict__ kI, u16* __restrict__ vI)
{
    const int tid = threadIdx.x;
    const int L = blockIdx.x + 2 * (blockIdx.y + 12 * blockIdx.z);
    const int idx = L >> 3;                 // 0..191
    const int b  = (L & 7) * 8 + idx / 24;  // contiguous b-chunk per XCD
    const int r  = idx % 24;
    const int mt = r >> 1, nt = r & 1;
    v4f acc[4][4] = {};
    gemm_direct<12>(WbI + (size_t)mt * 49152,
                    xI + ((size_t)b * 2 + nt) * 49152, acc, tid);

    const int lane = tid & 63, w = tid >> 6;
    const int wm = (w & 1) * 64, wn = (w >> 1) * 64;
    const int quad = lane >> 4, l16 = lane & 15;
    #pragma unroll
    for (int i = 0; i < 4; i++) {
        #pragma unroll
        for (int j = 0; j < 4; j++) {
            int gc = mt * 128 + wm + i * 16 + quad * 4;  // global channel base
            int n  = nt * 128 + wn + j * 16 + l16;       // token (0..255)
            v4f v = acc[i][j];
            if (gc < 256) {            // q
                v4f s = *(const v4f*)&TB[gc];
                v4f t = *(const v4f*)&TB[256 + gc];
                v4u u;
                #pragma unroll
                for (int r2 = 0; r2 < 4; r2++) u[r2] = f2bf(v[r2] * s[r2] + t[r2]);
                *(v4u*)&qI[((size_t)(b * 8 + (gc >> 5)) * 256 + n) * 32 + (gc & 31)] = u;
            } else if (gc < 512) {     // k
                int c = gc - 256;
                v4f s = *(const v4f*)&TB[512 + c];
                v4f t = *(const v4f*)&TB[768 + c];
                v4u u;
                #pragma unroll
                for (int r2 = 0; r2 < 4; r2++) u[r2] = f2bf(v[r2] * s[r2] + t[r2]);
                *(v4u*)&kI[((size_t)(b * 8 + (c >> 5)) * 256 + n) * 32 + (c & 31)] = u;
            } else {                   // v -> image (row = e, col = n as k-dim)
                int c = gc - 512;      // 0..1023
                if (n < 224) {
                    int o = c >> 7, e = c & 127;
                    u16* base = vI + ((size_t)(b * 8 + o) * 7 + (n >> 5)) * 4096
                                + ((n >> 3) & 3) * 1024 + (n & 7);
                    #pragma unroll
                    for (int r2 = 0; r2 < 4; r2++) {
                        u16 outv = 0;
                        if (n < N_) outv = f2bf(v[r2] * TB[1024 + c + r2] + TB[2048 + c + r2]);
                        base[(e + r2) * 8] = outv;
                    }
                }
            }
        }
    }
}

// ---------------------------------------------------------------------------
// K2: depthwise 3x3 conv. Block = 64 channels of one (b,o).
// ---------------------------------------------------------------------------
__global__ __launch_bounds__(256) void k_dwconv(
    const u16* __restrict__ vI, const float* __restrict__ wvl,
    const float* __restrict__ TB, u16* __restrict__ vlocI)
{
    __shared__ u16 V[64 * 230];             // 29440 B
    const int tid = threadIdx.x;
    const int sub = blockIdx.x;             // 0..15: o = sub>>1, half = sub&1
    const int b   = blockIdx.y;
    const int o   = sub >> 1;
    const int e0  = (sub & 1) * 64;
    const u16* img = vI + (size_t)(b * 8 + o) * 28672;

    {
        const int quad = tid >> 6, l = tid & 63;
        #pragma unroll
        for (int i = 0; i < 7; i++) {
            v8s u = *(const v8s*)&img[i * 4096 + quad * 1024 + (e0 + l) * 8];
            const u32* ui = (const u32*)&u;
            int m0 = i * 32 + quad * 8;
            u32* dst = (u32*)&V[l * 230 + m0];
            #pragma unroll
            for (int c = 0; c < 4; c++) dst[c] = ui[c];
        }
    }
    __syncthreads();

    const int e = tid & 63, j = tid >> 6;
    const int cg = sub * 64 + e;
    const int y0 = j * 4;
    const int ny = (j == 3) ? 2 : 4;
    float wgt[9];
    #pragma unroll
    for (int k = 0; k < 9; k++) wgt[k] = wvl[cg * 9 + k];
    const float sc = TB[3840 + cg], sh = TB[4864 + cg];
    u32 po[4][7];

    for (int yi = 0; yi < ny; yi++) {
        int y = y0 + yi;
        float a[3][16];
        #pragma unroll
        for (int dy = 0; dy < 3; dy++) {
            int yy = y + dy - 1;
            a[dy][0] = 0.f; a[dy][15] = 0.f;
            if (yy < 0 || yy > 13) {
                #pragma unroll
                for (int x = 1; x < 15; x++) a[dy][x] = 0.f;
            } else {
                const u16* rp = &V[e * 230 + yy * 14];
                #pragma unroll
                for (int c4 = 0; c4 < 7; c4++) {
                    u32 u = *(const u32*)&rp[c4 * 2];
                    a[dy][1 + 2 * c4] = bf2f((u16)(u & 0xffffu));
                    a[dy][2 + 2 * c4] = bf2f((u16)(u >> 16));
                }
            }
        }
        #pragma unroll
        for (int xp = 0; xp < 7; xp++) {
            u32 pk = 0;
            #pragma unroll
            for (int half = 0; half < 2; half++) {
                int x = 2 * xp + half;
                float s = 0.f;
                #pragma unroll
                for (int dy = 0; dy < 3; dy++)
                    #pragma unroll
                    for (int kx = 0; kx < 3; kx++)
                        s += wgt[dy * 3 + kx] * a[dy][x + kx];
                u16 bv = f2bf(s * sc + sh);
                pk |= ((u32)bv) << (16 * half);
            }
            po[yi][xp] = pk;
        }
    }
    __syncthreads();

    for (int yi = 0; yi < ny; yi++) {
        u32* dst = (u32*)&V[e * 196 + (y0 + yi) * 14];
        #pragma unroll
        for (int xp = 0; xp < 7; xp++) dst[xp] = po[yi][xp];
    }
    __syncthreads();

    for (int it = 0; it < 7; it++) {
        int idx = it * 256 + tid;
        if (idx < 1568) {
            int g = idx / 196, n = idx - g * 196;
            v4u lo, hi;
            #pragma unroll
            for (int r = 0; r < 4; r++) lo[r] = V[(g * 8 + r) * 196 + n];
            #pragma unroll
            for (int r = 0; r < 4; r++) hi[r] = V[(g * 8 + 4 + r) * 196 + n];
            u16* dst = vlocI + ((size_t)(b * 2 + (n >> 7)) * 32 + sub * 2 + (g >> 2)) * 4096
                     + (g & 3) * 1024 + (n & 127) * 8;
            *(v4u*)dst = lo;
            *(v4u*)(dst + 4) = hi;
        }
    }
}

// ---------------------------------------------------------------------------
// K3: FUSED attention + AV + vloc + relu -> aoI. 512 threads / 8 waves:
// phase A: wave -> 1 head; phase B: thread -> (column m, q-half);
// phase C: wave -> 1 output head. Same grid (25, B) so each phase's wall
// time halves vs the 256-thread version while LDS stays 30.7 KB
// (4 resident blocks/CU = 32 waves, wave-slot capped).
// XCD swizzle: 1600 blocks = 8 XCDs x (8 b x 25 qt).
// ---------------------------------------------------------------------------
__global__ __launch_bounds__(512) void k_attn_av(
    const u16* __restrict__ qI, const u16* __restrict__ kI,
    const u16* __restrict__ vI,
    const float* __restrict__ th1w,
    const float* __restrict__ th2w, const float* __restrict__ th2b,
    const float* __restrict__ biasE,
    const u16* __restrict__ vlocI, u16* __restrict__ aoI)
{
    __shared__ u16 Sl[8 * 8 * 228];   // [h][q][m] = 29184 B
    __shared__ float red[64][8];
    __shared__ float invS[64];        // [h*8+q]
    const int tid = threadIdx.x;
    const int w = tid >> 6, lane = tid & 63;
    const int quad = lane >> 4, l16 = lane & 15;
    const int L = blockIdx.x + 25 * blockIdx.y;
    const int idx = L >> 3;                 // 0..199
    const int b  = (L & 7) * 8 + idx / 25;  // contiguous b-chunk per XCD
    const int qt = idx % 25;                // 0..24
    const int n0 = qt * 8;

    // phase A: wave w -> head w
    {
        const int h = w;
        const u16* qb = qI + (size_t)(b * 8 + h) * 8192;
        const u16* kb = kI + (size_t)(b * 8 + h) * 8192;
        v8s a = *(const v8s*)&qb[(n0 + l16) * 32 + quad * 8];
        #pragma unroll
        for (int mt = 0; mt < 13; mt++) {
            v8s bfr = *(const v8s*)&kb[(mt * 16 + l16) * 32 + quad * 8];
            v4f acc = {};
            acc = __builtin_amdgcn_mfma_f32_16x16x32_bf16(a, bfr, acc, 0, 0, 0);
            if (quad < 2) {
                #pragma unroll
                for (int r = 0; r < 4; r++) {
                    int q = quad * 4 + r;
                    Sl[(h * 8 + q) * 228 + mt * 16 + l16] = f2h(acc[r]);
                }
            }
        }
    }
    __syncthreads();

    // phase B1: thread owns (column m, q-half); coalesced biasE reads
    const int m = tid & 255;
    const int qh = tid >> 8;          // 0 or 1 -> q = qh*4 + qq
    const bool mact = (m < N_);
    for (int qq = 0; qq < 4; qq++) {
        int q = qh * 4 + qq;
        int n = n0 + q;
        if (mact && n < N_) {
            const float* bE = biasE + (size_t)n * 1568 + m;
            float S[8];
            #pragma unroll
            for (int h = 0; h < 8; h++) S[h] = h2f(Sl[(h * 8 + q) * 228 + m]);
            float E[8];
            #pragma unroll
            for (int o = 0; o < 8; o++) {
                float a = bE[o * 196];
                #pragma unroll
                for (int h = 0; h < 8; h++) a += th1w[o * 8 + h] * S[h];
                E[o] = __expf(a);
            }
            #pragma unroll
            for (int o = 0; o < 8; o++)
                Sl[(o * 8 + q) * 228 + m] = f2h(E[o]);
        }
    }
    __syncthreads();

    // phase B2: 64 rows x 8 octants; vectorized u32 LDS reads (m < 196)
    {
        int r = tid >> 3, oct = tid & 7;
        int mstart = oct * 24;
        int cnt = (oct == 7) ? 14 : 12;   // u32 pairs: 7*24 + 28 = 196
        const u16* rowp = &Sl[r * 228 + mstart];
        float s = 0.f;
        for (int i = 0; i < cnt; i++) {
            u32 u = *(const u32*)&rowp[i * 2];
            s += h2f((u16)(u & 0xffffu)) + h2f((u16)(u >> 16));
        }
        red[r][oct] = s;
    }
    __syncthreads();
    if (tid < 64) {
        float s = 0.f;
        #pragma unroll
        for (int i = 0; i < 8; i++) s += red[tid][i];
        invS[tid] = 1.f / s;
    }
    __syncthreads();

    // phase B3: scale + TH2 in place (bf16); 4 q per thread
    for (int qq = 0; qq < 4; qq++) {
        int q = qh * 4 + qq;
        bool valid = mact && (n0 + q < N_);
        float p[8];
        if (valid) {
            float sc[8];
            #pragma unroll
            for (int h = 0; h < 8; h++)
                sc[h] = h2f(Sl[(h * 8 + q) * 228 + m]) * invS[h * 8 + q];
            #pragma unroll
            for (int o = 0; o < 8; o++) {
                float v = th2b[o];
                #pragma unroll
                for (int h = 0; h < 8; h++) v += th2w[o * 8 + h] * sc[h];
                p[o] = v;
            }
        }
        if (m < 224) {
            #pragma unroll
            for (int o = 0; o < 8; o++)
                Sl[(o * 8 + q) * 228 + m] = valid ? f2bf(p[o]) : (u16)0;
        }
    }
    __syncthreads();

    // phase C: AV. Wave w handles o = w.
    // A = vI fragments (global, image order); B = Sl rows (P, bf16).
    // B rows l16>=8 duplicate rows 0..7 -> output cols 8..15 discarded.
    {
        const int half_ = n0 >> 7;
        const int row0 = n0 & 127;
        const int n = n0 + l16;
        const bool act = (l16 < 8) && (n < N_);
        const int o = w;
        const u16* vb = vI + (size_t)(b * 8 + o) * 28672;
        const u16* prow = &Sl[(o * 8 + (l16 & 7)) * 228];
        #pragma unroll
        for (int eh = 0; eh < 2; eh++) {       // 2 e-halves of 64
            v4f acc[4] = {};
            v8s a[2][4];
            const u16* ab0 = vb + quad * 1024 + (eh * 64 + l16) * 8;
            #pragma unroll
            for (int e = 0; e < 4; e++) a[0][e] = *(const v8s*)(ab0 + e * 128);
            #pragma unroll
            for (int ks = 0; ks < 7; ks++) {
                const int cur = ks & 1, nxt = cur ^ 1;
                if (ks < 6) {
                    const u16* an = ab0 + (size_t)(ks + 1) * 4096;
                    #pragma unroll
                    for (int e = 0; e < 4; e++) a[nxt][e] = *(const v8s*)(an + e * 128);
                }
                v8s bfr = *(const v8s*)&prow[ks * 32 + quad * 8];
                #pragma unroll
                for (int e = 0; e < 4; e++)
                    acc[e] = __builtin_amdgcn_mfma_f32_16x16x32_bf16(a[cur][e], bfr, acc[e], 0, 0, 0);
            }
            if (act) {
                #pragma unroll
                for (int e = 0; e < 4; e++) {
                    const int c0 = o * 128 + (eh * 4 + e) * 16 + quad * 4;
                    const size_t ioff = ((size_t)(b * 2 + half_) * 32 + (c0 >> 5)) * 4096
                                      + ((c0 >> 3) & 3) * 1024 + (size_t)(row0 + l16) * 8 + (c0 & 7);
                    v4u lv = *(const v4u*)&vlocI[ioff];
                    v4u u;
                    #pragma unroll
                    for (int r = 0; r < 4; r++)
                        u[r] = f2bf(fmaxf(acc[e][r] + bf2f(lv[r]), 0.f));
                    *(v4u*)&aoI[ioff] = u;
                }
            }
        }
    }
}

// ---------------------------------------------------------------------------
// K6: projection GEMM (direct core, K=1024) + BN -> out fp32
// XCD swizzle: 384 blocks = 8 XCDs x (8 b x 6 tiles).
// ---------------------------------------------------------------------------
__global__ __launch_bounds__(256) void k_proj(
    const u16* __restrict__ WpI, const u16* __restrict__ aoI,
    const float* __restrict__ TB, float* __restrict__ out)
{
    const int tid = threadIdx.x;
    const int L = blockIdx.x + 2 * (blockIdx.y + 3 * blockIdx.z);
    const int idx = L >> 3;                 // 0..47
    const int b  = (L & 7) * 8 + idx / 6;   // contiguous b-chunk per XCD
    const int r  = idx % 6;
    const int mt = r >> 1, nt = r & 1;
    v4f acc[4][4] = {};
    gemm_direct<32>(WpI + (size_t)mt * 131072,
                    aoI + ((size_t)b * 2 + nt) * 131072, acc, tid);

    const int lane = tid & 63, w = tid >> 6;
    const int wm = (w & 1) * 64, wn = (w >> 1) * 64;
    const int quad = lane >> 4, l16 = lane & 15;
    #pragma unroll
    for (int i = 0; i < 4; i++) {
        #pragma unroll
        for (int j = 0; j < 4; j++) {
            int p0 = mt * 128 + wm + i * 16 + quad * 4;
            int n  = nt * 128 + wn + j * 16 + l16;
            if (n < N_) {
                v4f s = *(const v4f*)&TB[3072 + p0];
                v4f t = *(const v4f*)&TB[3456 + p0];
                #pragma unroll
                for (int r2 = 0; r2 < 4; r2++)
                    out[((size_t)b * DIM_ + p0 + r2) * N_ + n] = acc[i][j][r2] * s[r2] + t[r2];
            }
        }
    }
}

// ---------------------------------------------------------------------------
extern "C" void kernel_launch(void* const* d_in, const int* in_sizes, int n_in,
                              void* d_out, int out_size, void* d_ws, size_t ws_size,
                              hipStream_t stream)
{
    const float* x    = (const float*)d_in[0];
    const float* wq   = (const float*)d_in[1];
    const float* bq   = (const float*)d_in[2];
    const float* bnq  = (const float*)d_in[3];
    const float* wk   = (const float*)d_in[4];
    const float* bk   = (const float*)d_in[5];
    const float* bnk  = (const float*)d_in[6];
    const float* wv   = (const float*)d_in[7];
    const float* bv   = (const float*)d_in[8];
    const float* bnv  = (const float*)d_in[9];
    const float* wvl  = (const float*)d_in[10];
    const float* bvl  = (const float*)d_in[11];
    const float* bnvl = (const float*)d_in[12];
    const float* th1w = (const float*)d_in[13];
    const float* th1b = (const float*)d_in[14];
    const float* th2w = (const float*)d_in[15];
    const float* th2b = (const float*)d_in[16];
    const float* wp   = (const float*)d_in[17];
    const float* bp   = (const float*)d_in[18];
    const float* bnp  = (const float*)d_in[19];
    const float* ab   = (const float*)d_in[20];
    const int*   bidx = (const int*)d_in[21];
    float* out = (float*)d_out;

    u16* wsb  = (u16*)d_ws;
    u16* WbI  = wsb + WBI_OFF;
    u16* WpI  = wsb + WPI_OFF;
    u16* qI   = wsb + QI_OFF;
    u16* kI   = wsb + KI_OFF;
    u16* vI   = wsb + VI_OFF;
    u16* vlocI = wsb + VLOC_U16;
    u16* xI   = wsb + TAIL_OFF;   // aliased: xI -> aoI (disjoint lifetimes)
    u16* aoI  = wsb + TAIL_OFF;
    float* TB    = (float*)(wsb + TB_OFF);
    float* abT1  = (float*)(wsb + ABT_OFF);
    float* biasE = (float*)(wsb + BIASE_OFF);

    k_castW<<<dim3(3859), 256, 0, stream>>>(wq, wk, wv, wp, ab, th1w, th1b,
                                            bq, bnq, bk, bnk, bv, bnv, bp, bnp, bvl, bnvl,
                                            WbI, WpI, abT1, TB);
    k_bias<<<dim3((N_ * 8 * N_ + 255) / 256), 256, 0, stream>>>(abT1, bidx, biasE);
    k_castX<<<dim3(4, 6, B_), 256, 0, stream>>>(x, xI);
    k_qkv<<<dim3(2, 12, B_), 256, 0, stream>>>(WbI, xI, TB, qI, kI, vI);
    k_dwconv<<<dim3(16, B_), 256, 0, stream>>>(vI, wvl, TB, vlocI);
    k_attn_av<<<dim3(25, B_), 512, 0, stream>>>(qI, kI, vI, th1w, th2w, th2b,
                                                biasE, vlocI, aoI);
    k_proj<<<dim3(2, 3, B_), 256, 0, stream>>>(WpI, aoI, TB, out);
}

// Round 3
// 268.189 us; speedup vs baseline: 1.1192x; 1.0071x over previous
//
#include <hip/hip_runtime.h>

#define B_     64
#define DIM_   384
#define RES_   14
#define N_     196
#define HEADS_ 8
#define KD_    32
#define D_     128
#define DH_    1024
#define QK_    256
#define CH_    1536
#define EPS_   1e-5f
#define SCALE_ 0.17677669529663687f   // 32^-0.5

typedef unsigned short u16;
typedef unsigned int u32;
typedef short v8s __attribute__((ext_vector_type(8)));
typedef float v4f __attribute__((ext_vector_type(4)));
typedef u16  v4u __attribute__((ext_vector_type(4)));

static __device__ __forceinline__ u16 f2bf(float f) {
    unsigned int u = __builtin_bit_cast(unsigned int, f);
    u = (u + 0x7fffu + ((u >> 16) & 1u)) >> 16;
    return (u16)u;
}
static __device__ __forceinline__ float bf2f(u16 u) {
    unsigned int x = ((unsigned int)u) << 16;
    return __builtin_bit_cast(float, x);
}
static __device__ __forceinline__ u16 f2h(float f) {
    _Float16 h = (_Float16)f;
    return __builtin_bit_cast(u16, h);
}
static __device__ __forceinline__ float h2f(u16 u) {
    return (float)__builtin_bit_cast(_Float16, u);
}

// workspace layout (u16 element offsets)
// GEMM operand images: [kstep][kquad(4)][row(128)][8] = 4096 elems (8KB)/kstep
#define WBI_OFF  0u          // Wb  image: 12 mtiles x 12 ksteps      (589824)
#define WPI_OFF  589824u     // wp  image: 3 mtiles x 32 ksteps       (393216)
#define QI_OFF   983040u     // qT  [B][8][256][32]                   (4194304)
#define KI_OFF   5177344u    // kT  [B][8][256][32]                   (4194304)
#define VI_OFF   9371648u    // v   image: [B][8] x 7 ksteps          (14680064)
#define VLOC_U16 53411840u   // vlocI in aoI image layout             (16777216)
#define TAIL_OFF 79101952u   // union: xI (6291456) / aoI (16777216)
#define TB_OFF   98770944u   // BN tables fp32[5888]
#define ABT_OFF  98782720u   // abT1 [196][8] fp32 (th1-folded bias)
#define BIASE_OFF 98785920u  // biasE [196][8][196] fp32 (614656 u16)

// ---------------------------------------------------------------------------
// barrier-free direct-from-global 128x128 MFMA core. Operands pre-packed in
// fragment order; 2-deep software pipeline, NO LDS, NO __syncthreads.
// ---------------------------------------------------------------------------
template<int KSTEPS>
static __device__ __forceinline__ void gemm_direct(
    const u16* __restrict__ Ag, const u16* __restrict__ Bg,
    v4f acc[4][4], int tid)
{
    const int lane = tid & 63, w = tid >> 6;
    const int wm = (w & 1) * 64, wn = (w >> 1) * 64;
    const int quad = lane >> 4, l16 = lane & 15;
    const u16* pa = Ag + quad * 1024 + (wm + l16) * 8;
    const u16* pb = Bg + quad * 1024 + (wn + l16) * 8;
    v8s a[2][4], b[2][4];
    #pragma unroll
    for (int i = 0; i < 4; i++) {
        a[0][i] = *(const v8s*)(pa + i * 128);
        b[0][i] = *(const v8s*)(pb + i * 128);
    }
    #pragma unroll
    for (int ks = 0; ks < KSTEPS; ks++) {
        const int cur = ks & 1, nxt = cur ^ 1;
        if (ks + 1 < KSTEPS) {
            const u16* qa = pa + (size_t)(ks + 1) * 4096;
            const u16* qb = pb + (size_t)(ks + 1) * 4096;
            #pragma unroll
            for (int i = 0; i < 4; i++) {
                a[nxt][i] = *(const v8s*)(qa + i * 128);
                b[nxt][i] = *(const v8s*)(qb + i * 128);
            }
        }
        #pragma unroll
        for (int i = 0; i < 4; i++)
            #pragma unroll
            for (int j = 0; j < 4; j++)
                acc[i][j] = __builtin_amdgcn_mfma_f32_16x16x32_bf16(a[cur][i], b[cur][j], acc[i][j], 0, 0, 0);
    }
}

// ---------------------------------------------------------------------------
// pack weights into tile images + abT1 (th1-folded bias) + BN tables
// ---------------------------------------------------------------------------
__global__ __launch_bounds__(256) void k_castW(
    const float* __restrict__ wq, const float* __restrict__ wk,
    const float* __restrict__ wv, const float* __restrict__ wp,
    const float* __restrict__ ab,
    const float* __restrict__ th1w, const float* __restrict__ th1b,
    const float* __restrict__ bq, const float* __restrict__ bnq,
    const float* __restrict__ bk, const float* __restrict__ bnk,
    const float* __restrict__ bv, const float* __restrict__ bnv,
    const float* __restrict__ bp, const float* __restrict__ bnp,
    const float* __restrict__ bvl, const float* __restrict__ bnvl,
    u16* __restrict__ WbI, u16* __restrict__ WpI,
    float* __restrict__ abT1, float* __restrict__ TB)
{
    int i = blockIdx.x * 256 + threadIdx.x;
    if (i < 589824) {           // qkv weight image
        int mt = i / 49152, rem = i % 49152;
        int ks = rem >> 12, r2 = rem & 4095;
        int q = r2 >> 10, row = (r2 >> 3) & 127, e = r2 & 7;
        int c = mt * 128 + row, k = ks * 32 + q * 8 + e;
        float v = (c < 256) ? wq[c * 384 + k]
                : (c < 512) ? wk[(c - 256) * 384 + k]
                            : wv[(size_t)(c - 512) * 384 + k];
        WbI[i] = f2bf(v);
    } else if (i < 983040) {    // proj weight image
        int j = i - 589824;
        int mt = j >> 17, rem = j & 131071;
        int ks = rem >> 12, r2 = rem & 4095;
        int q = r2 >> 10, row = (r2 >> 3) & 127, e = r2 & 7;
        int p = mt * 128 + row, k = ks * 32 + q * 8 + e;
        WpI[j] = f2bf(wp[(size_t)p * 1024 + k]);
    } else if (i < 984608) {    // abT1[idx][o] = th1b[o] + sum_h th1w[o][h]*ab[h][idx]
        int j = i - 983040;
        int idx = j >> 3, o = j & 7;
        float a = th1b[o];
        #pragma unroll
        for (int h = 0; h < 8; h++) a += th1w[o * 8 + h] * ab[h * N_ + idx];
        abT1[j] = a;
    } else if (i < 987552) {    // BN tables
        int j = i - 984608;
        if (j < 256) {
            int c = j;
            float s = bnq[c] * rsqrtf(bnq[768 + c] + EPS_);
            float t = (bq[c] - bnq[512 + c]) * s + bnq[256 + c];
            TB[c] = s * SCALE_; TB[256 + c] = t * SCALE_;
        } else if (j < 512) {
            int c = j - 256;
            float s = bnk[c] * rsqrtf(bnk[768 + c] + EPS_);
            float t = (bk[c] - bnk[512 + c]) * s + bnk[256 + c];
            TB[512 + c] = s; TB[768 + c] = t;
        } else if (j < 1536) {
            int c = j - 512;
            float s = bnv[c] * rsqrtf(bnv[3072 + c] + EPS_);
            float t = (bv[c] - bnv[2048 + c]) * s + bnv[1024 + c];
            TB[1024 + c] = s; TB[2048 + c] = t;
        } else if (j < 1920) {
            int c = j - 1536;
            float s = bnp[c] * rsqrtf(bnp[1152 + c] + EPS_);
            float t = (bp[c] - bnp[768 + c]) * s + bnp[384 + c];
            TB[3072 + c] = s; TB[3456 + c] = t;
        } else {
            int c = j - 1920;
            float s = bnvl[c] * rsqrtf(bnvl[3072 + c] + EPS_);
            float t = (bvl[c] - bnvl[2048 + c]) * s + bnvl[1024 + c];
            TB[3840 + c] = s; TB[4864 + c] = t;
        }
    }
}

// ---------------------------------------------------------------------------
// expand bias: biasE[n][o][m] = abT1[bidx[n][m]][o] - 5  (batch-independent)
// ---------------------------------------------------------------------------
__global__ __launch_bounds__(256) void k_bias(
    const float* __restrict__ abT1, const int* __restrict__ bidx,
    float* __restrict__ biasE)
{
    int i = blockIdx.x * 256 + threadIdx.x;
    if (i >= N_ * 8 * N_) return;
    int m = i % N_;
    int t = i / N_;
    int o = t & 7;
    int n = t >> 3;
    biasE[i] = abT1[bidx[n * N_ + m] * 8 + o] - 5.f;
}

// ---------------------------------------------------------------------------
// x [B,384,196] fp32 -> xI image [B][nt2][12 ksteps][4096] bf16 (n>=196 zero)
// ---------------------------------------------------------------------------
__global__ __launch_bounds__(256) void k_castX(
    const float* __restrict__ x, u16* __restrict__ xI)
{
    __shared__ float T[64][65];
    const int tid = threadIdx.x;
    const int n0 = blockIdx.x * 64;
    const int k0 = blockIdx.y * 64;
    const int b  = blockIdx.z;
    const int c = tid & 63, r4 = tid >> 6;
    #pragma unroll
    for (int i = 0; i < 16; i++) {
        int kr = i * 4 + r4;
        int gn = n0 + c;
        T[kr][c] = (gn < N_) ? x[((size_t)b * DIM_ + k0 + kr) * N_ + gn] : 0.f;
    }
    __syncthreads();
    #pragma unroll
    for (int it = 0; it < 16; it++) {
        int j = it * 256 + tid;
        int kk = j & 63, nn = j >> 6;
        int k = k0 + kk, n = n0 + nn;
        xI[(size_t)b * 98304 + (n >> 7) * 49152 + (k >> 5) * 4096
           + ((k >> 3) & 3) * 1024 + (n & 127) * 8 + (k & 7)] = f2bf(T[kk][nn]);
    }
}

// ---------------------------------------------------------------------------
// K1: QKV GEMM (direct core). qI/kI [b][h][256][32] bf16 (q pre-scaled),
// vI image per (b,o), 7 ksteps (n>=196 zero).
// XCD swizzle: 1536 blocks = 8 XCDs x (8 b x 24 tiles).
// ---------------------------------------------------------------------------
__global__ __launch_bounds__(256) void k_qkv(
    const u16* __restrict__ WbI, const u16* __restrict__ xI,
    const float* __restrict__ TB,
    u16* __restrict__ qI, u16* __restrict__ kI, u16* __restrict__ vI)
{
    const int tid = threadIdx.x;
    const int L = blockIdx.x + 2 * (blockIdx.y + 12 * blockIdx.z);
    const int idx = L >> 3;                 // 0..191
    const int b  = (L & 7) * 8 + idx / 24;  // contiguous b-chunk per XCD
    const int r  = idx % 24;
    const int mt = r >> 1, nt = r & 1;
    v4f acc[4][4] = {};
    gemm_direct<12>(WbI + (size_t)mt * 49152,
                    xI + ((size_t)b * 2 + nt) * 49152, acc, tid);

    const int lane = tid & 63, w = tid >> 6;
    const int wm = (w & 1) * 64, wn = (w >> 1) * 64;
    const int quad = lane >> 4, l16 = lane & 15;
    #pragma unroll
    for (int i = 0; i < 4; i++) {
        #pragma unroll
        for (int j = 0; j < 4; j++) {
            int gc = mt * 128 + wm + i * 16 + quad * 4;  // global channel base
            int n  = nt * 128 + wn + j * 16 + l16;       // token (0..255)
            v4f v = acc[i][j];
            if (gc < 256) {            // q
                v4f s = *(const v4f*)&TB[gc];
                v4f t = *(const v4f*)&TB[256 + gc];
                v4u u;
                #pragma unroll
                for (int r2 = 0; r2 < 4; r2++) u[r2] = f2bf(v[r2] * s[r2] + t[r2]);
                *(v4u*)&qI[((size_t)(b * 8 + (gc >> 5)) * 256 + n) * 32 + (gc & 31)] = u;
            } else if (gc < 512) {     // k
                int c = gc - 256;
                v4f s = *(const v4f*)&TB[512 + c];
                v4f t = *(const v4f*)&TB[768 + c];
                v4u u;
                #pragma unroll
                for (int r2 = 0; r2 < 4; r2++) u[r2] = f2bf(v[r2] * s[r2] + t[r2]);
                *(v4u*)&kI[((size_t)(b * 8 + (c >> 5)) * 256 + n) * 32 + (c & 31)] = u;
            } else {                   // v -> image (row = e, col = n as k-dim)
                int c = gc - 512;      // 0..1023
                if (n < 224) {
                    int o = c >> 7, e = c & 127;
                    u16* base = vI + ((size_t)(b * 8 + o) * 7 + (n >> 5)) * 4096
                                + ((n >> 3) & 3) * 1024 + (n & 7);
                    #pragma unroll
                    for (int r2 = 0; r2 < 4; r2++) {
                        u16 outv = 0;
                        if (n < N_) outv = f2bf(v[r2] * TB[1024 + c + r2] + TB[2048 + c + r2]);
                        base[(e + r2) * 8] = outv;
                    }
                }
            }
        }
    }
}

// ---------------------------------------------------------------------------
// K2: depthwise 3x3 conv. Block = 64 channels of one (b,o).
// ---------------------------------------------------------------------------
__global__ __launch_bounds__(256) void k_dwconv(
    const u16* __restrict__ vI, const float* __restrict__ wvl,
    const float* __restrict__ TB, u16* __restrict__ vlocI)
{
    __shared__ u16 V[64 * 230];             // 29440 B
    const int tid = threadIdx.x;
    const int sub = blockIdx.x;             // 0..15: o = sub>>1, half = sub&1
    const int b   = blockIdx.y;
    const int o   = sub >> 1;
    const int e0  = (sub & 1) * 64;
    const u16* img = vI + (size_t)(b * 8 + o) * 28672;

    {
        const int quad = tid >> 6, l = tid & 63;
        #pragma unroll
        for (int i = 0; i < 7; i++) {
            v8s u = *(const v8s*)&img[i * 4096 + quad * 1024 + (e0 + l) * 8];
            const u32* ui = (const u32*)&u;
            int m0 = i * 32 + quad * 8;
            u32* dst = (u32*)&V[l * 230 + m0];
            #pragma unroll
            for (int c = 0; c < 4; c++) dst[c] = ui[c];
        }
    }
    __syncthreads();

    const int e = tid & 63, j = tid >> 6;
    const int cg = sub * 64 + e;
    const int y0 = j * 4;
    const int ny = (j == 3) ? 2 : 4;
    float wgt[9];
    #pragma unroll
    for (int k = 0; k < 9; k++) wgt[k] = wvl[cg * 9 + k];
    const float sc = TB[3840 + cg], sh = TB[4864 + cg];
    u32 po[4][7];

    for (int yi = 0; yi < ny; yi++) {
        int y = y0 + yi;
        float a[3][16];
        #pragma unroll
        for (int dy = 0; dy < 3; dy++) {
            int yy = y + dy - 1;
            a[dy][0] = 0.f; a[dy][15] = 0.f;
            if (yy < 0 || yy > 13) {
                #pragma unroll
                for (int x = 1; x < 15; x++) a[dy][x] = 0.f;
            } else {
                const u16* rp = &V[e * 230 + yy * 14];
                #pragma unroll
                for (int c4 = 0; c4 < 7; c4++) {
                    u32 u = *(const u32*)&rp[c4 * 2];
                    a[dy][1 + 2 * c4] = bf2f((u16)(u & 0xffffu));
                    a[dy][2 + 2 * c4] = bf2f((u16)(u >> 16));
                }
            }
        }
        #pragma unroll
        for (int xp = 0; xp < 7; xp++) {
            u32 pk = 0;
            #pragma unroll
            for (int half = 0; half < 2; half++) {
                int x = 2 * xp + half;
                float s = 0.f;
                #pragma unroll
                for (int dy = 0; dy < 3; dy++)
                    #pragma unroll
                    for (int kx = 0; kx < 3; kx++)
                        s += wgt[dy * 3 + kx] * a[dy][x + kx];
                u16 bv = f2bf(s * sc + sh);
                pk |= ((u32)bv) << (16 * half);
            }
            po[yi][xp] = pk;
        }
    }
    __syncthreads();

    for (int yi = 0; yi < ny; yi++) {
        u32* dst = (u32*)&V[e * 196 + (y0 + yi) * 14];
        #pragma unroll
        for (int xp = 0; xp < 7; xp++) dst[xp] = po[yi][xp];
    }
    __syncthreads();

    for (int it = 0; it < 7; it++) {
        int idx = it * 256 + tid;
        if (idx < 1568) {
            int g = idx / 196, n = idx - g * 196;
            v4u lo, hi;
            #pragma unroll
            for (int r = 0; r < 4; r++) lo[r] = V[(g * 8 + r) * 196 + n];
            #pragma unroll
            for (int r = 0; r < 4; r++) hi[r] = V[(g * 8 + 4 + r) * 196 + n];
            u16* dst = vlocI + ((size_t)(b * 2 + (n >> 7)) * 32 + sub * 2 + (g >> 2)) * 4096
                     + (g & 3) * 1024 + (n & 127) * 8;
            *(v4u*)dst = lo;
            *(v4u*)(dst + 4) = hi;
        }
    }
}

// ---------------------------------------------------------------------------
// K3: FUSED attention + AV + vloc + relu -> aoI. 512 threads / 8 waves.
// LDS-pipe-lean layout: phase A swaps MFMA operands (D[m][q]) so each lane
// packs 4 consecutive-m values into one ds_write_b64 (13 vs 104 LDS ops);
// phases B1/B3 use m-pair threads so every LDS access is u32 (half the ops).
// XCD swizzle: 1600 blocks = 8 XCDs x (8 b x 25 qt).
// ---------------------------------------------------------------------------
__global__ __launch_bounds__(512) void k_attn_av(
    const u16* __restrict__ qI, const u16* __restrict__ kI,
    const u16* __restrict__ vI,
    const float* __restrict__ th1w,
    const float* __restrict__ th2w, const float* __restrict__ th2b,
    const float* __restrict__ biasE,
    const u16* __restrict__ vlocI, u16* __restrict__ aoI)
{
    __shared__ u16 Sl[8 * 8 * 228];   // [h][q][m] = 29184 B
    __shared__ float red[64][8];
    __shared__ float invS[64];        // [h*8+q]
    const int tid = threadIdx.x;
    const int w = tid >> 6, lane = tid & 63;
    const int quad = lane >> 4, l16 = lane & 15;
    const int L = blockIdx.x + 25 * blockIdx.y;
    const int idx = L >> 3;                 // 0..199
    const int b  = (L & 7) * 8 + idx / 25;  // contiguous b-chunk per XCD
    const int qt = idx % 25;                // 0..24
    const int n0 = qt * 8;

    // phase A: wave w -> head w. Operand-swapped MFMA: D[m_local][q].
    // Lane (quad, l16<8) holds 4 consecutive m -> single ds_write_b64.
    {
        const int h = w;
        const u16* qb = qI + (size_t)(b * 8 + h) * 8192;
        const u16* kb = kI + (size_t)(b * 8 + h) * 8192;
        v8s qf = *(const v8s*)&qb[(n0 + l16) * 32 + quad * 8];   // B operand (cols)
        #pragma unroll
        for (int mt = 0; mt < 13; mt++) {
            v8s kf = *(const v8s*)&kb[(mt * 16 + l16) * 32 + quad * 8]; // A operand (rows)
            v4f acc = {};
            acc = __builtin_amdgcn_mfma_f32_16x16x32_bf16(kf, qf, acc, 0, 0, 0);
            if (l16 < 8) {
                v4u pk;
                #pragma unroll
                for (int r = 0; r < 4; r++) pk[r] = f2h(acc[r]);
                *(v4u*)&Sl[(h * 8 + l16) * 228 + mt * 16 + quad * 4] = pk;
            }
        }
    }
    __syncthreads();

    // phase B1: thread owns (m-pair, q-pair); all LDS traffic u32, biasE float2
    const int mp  = (tid & 127) * 2;   // 0,2,...,254
    const int qh2 = tid >> 7;          // 0..3
    const bool pvalid = (mp < N_);     // N_=196 even -> pair fully valid/invalid
    for (int qq = 0; qq < 2; qq++) {
        int q = qh2 * 2 + qq;
        int n = n0 + q;
        if (pvalid && n < N_) {
            const float* bE = biasE + (size_t)n * 1568 + mp;
            float S0[8], S1[8];
            #pragma unroll
            for (int h = 0; h < 8; h++) {
                u32 u = *(const u32*)&Sl[(h * 8 + q) * 228 + mp];
                S0[h] = h2f((u16)(u & 0xffffu));
                S1[h] = h2f((u16)(u >> 16));
            }
            u32 ew[8];
            #pragma unroll
            for (int o = 0; o < 8; o++) {
                float2 bb = *(const float2*)&bE[o * 196];
                float a0 = bb.x, a1 = bb.y;
                #pragma unroll
                for (int h = 0; h < 8; h++) {
                    a0 += th1w[o * 8 + h] * S0[h];
                    a1 += th1w[o * 8 + h] * S1[h];
                }
                ew[o] = (u32)f2h(__expf(a0)) | ((u32)f2h(__expf(a1)) << 16);
            }
            #pragma unroll
            for (int o = 0; o < 8; o++)
                *(u32*)&Sl[(o * 8 + q) * 228 + mp] = ew[o];
        }
    }
    __syncthreads();

    // phase B2: 64 rows x 8 octants; vectorized u32 LDS reads (m < 196)
    {
        int r = tid >> 3, oct = tid & 7;
        int mstart = oct * 24;
        int cnt = (oct == 7) ? 14 : 12;   // u32 pairs: 7*24 + 28 = 196
        const u16* rowp = &Sl[r * 228 + mstart];
        float s = 0.f;
        for (int i = 0; i < cnt; i++) {
            u32 u = *(const u32*)&rowp[i * 2];
            s += h2f((u16)(u & 0xffffu)) + h2f((u16)(u >> 16));
        }
        red[r][oct] = s;
    }
    __syncthreads();
    if (tid < 64) {
        float s = 0.f;
        #pragma unroll
        for (int i = 0; i < 8; i++) s += red[tid][i];
        invS[tid] = 1.f / s;
    }
    __syncthreads();

    // phase B3: scale + TH2 in place (bf16); m-pair u32 traffic
    for (int qq = 0; qq < 2; qq++) {
        int q = qh2 * 2 + qq;
        bool valid = pvalid && (n0 + q < N_);
        u32 pw[8];
        if (valid) {
            float s0[8], s1[8];
            #pragma unroll
            for (int h = 0; h < 8; h++) {
                u32 u = *(const u32*)&Sl[(h * 8 + q) * 228 + mp];
                float is = invS[h * 8 + q];
                s0[h] = h2f((u16)(u & 0xffffu)) * is;
                s1[h] = h2f((u16)(u >> 16)) * is;
            }
            #pragma unroll
            for (int o = 0; o < 8; o++) {
                float v0 = th2b[o], v1 = th2b[o];
                #pragma unroll
                for (int h = 0; h < 8; h++) {
                    v0 += th2w[o * 8 + h] * s0[h];
                    v1 += th2w[o * 8 + h] * s1[h];
                }
                pw[o] = (u32)f2bf(v0) | ((u32)f2bf(v1) << 16);
            }
        } else {
            #pragma unroll
            for (int o = 0; o < 8; o++) pw[o] = 0;
        }
        if (mp < 224) {
            #pragma unroll
            for (int o = 0; o < 8; o++)
                *(u32*)&Sl[(o * 8 + q) * 228 + mp] = pw[o];
        }
    }
    __syncthreads();

    // phase C: AV. Wave w handles o = w.
    // A = vI fragments (global, image order); B = Sl rows (P, bf16).
    // B rows l16>=8 duplicate rows 0..7 -> output cols 8..15 discarded.
    {
        const int half_ = n0 >> 7;
        const int row0 = n0 & 127;
        const int n = n0 + l16;
        const bool act = (l16 < 8) && (n < N_);
        const int o = w;
        const u16* vb = vI + (size_t)(b * 8 + o) * 28672;
        const u16* prow = &Sl[(o * 8 + (l16 & 7)) * 228];
        __builtin_amdgcn_s_setprio(1);
        #pragma unroll
        for (int eh = 0; eh < 2; eh++) {       // 2 e-halves of 64
            v4f acc[4] = {};
            v8s a[2][4];
            const u16* ab0 = vb + quad * 1024 + (eh * 64 + l16) * 8;
            #pragma unroll
            for (int e = 0; e < 4; e++) a[0][e] = *(const v8s*)(ab0 + e * 128);
            #pragma unroll
            for (int ks = 0; ks < 7; ks++) {
                const int cur = ks & 1, nxt = cur ^ 1;
                if (ks < 6) {
                    const u16* an = ab0 + (size_t)(ks + 1) * 4096;
                    #pragma unroll
                    for (int e = 0; e < 4; e++) a[nxt][e] = *(const v8s*)(an + e * 128);
                }
                v8s bfr = *(const v8s*)&prow[ks * 32 + quad * 8];
                #pragma unroll
                for (int e = 0; e < 4; e++)
                    acc[e] = __builtin_amdgcn_mfma_f32_16x16x32_bf16(a[cur][e], bfr, acc[e], 0, 0, 0);
            }
            if (act) {
                #pragma unroll
                for (int e = 0; e < 4; e++) {
                    const int c0 = o * 128 + (eh * 4 + e) * 16 + quad * 4;
                    const size_t ioff = ((size_t)(b * 2 + half_) * 32 + (c0 >> 5)) * 4096
                                      + ((c0 >> 3) & 3) * 1024 + (size_t)(row0 + l16) * 8 + (c0 & 7);
                    v4u lv = *(const v4u*)&vlocI[ioff];
                    v4u u;
                    #pragma unroll
                    for (int r = 0; r < 4; r++)
                        u[r] = f2bf(fmaxf(acc[e][r] + bf2f(lv[r]), 0.f));
                    *(v4u*)&aoI[ioff] = u;
                }
            }
        }
        __builtin_amdgcn_s_setprio(0);
    }
}

// ---------------------------------------------------------------------------
// K6: projection GEMM (direct core, K=1024) + BN -> out fp32
// XCD swizzle: 384 blocks = 8 XCDs x (8 b x 6 tiles).
// ---------------------------------------------------------------------------
__global__ __launch_bounds__(256) void k_proj(
    const u16* __restrict__ WpI, const u16* __restrict__ aoI,
    const float* __restrict__ TB, float* __restrict__ out)
{
    const int tid = threadIdx.x;
    const int L = blockIdx.x + 2 * (blockIdx.y + 3 * blockIdx.z);
    const int idx = L >> 3;                 // 0..47
    const int b  = (L & 7) * 8 + idx / 6;   // contiguous b-chunk per XCD
    const int r  = idx % 6;
    const int mt = r >> 1, nt = r & 1;
    v4f acc[4][4] = {};
    gemm_direct<32>(WpI + (size_t)mt * 131072,
                    aoI + ((size_t)b * 2 + nt) * 131072, acc, tid);

    const int lane = tid & 63, w = tid >> 6;
    const int wm = (w & 1) * 64, wn = (w >> 1) * 64;
    const int quad = lane >> 4, l16 = lane & 15;
    #pragma unroll
    for (int i = 0; i < 4; i++) {
        #pragma unroll
        for (int j = 0; j < 4; j++) {
            int p0 = mt * 128 + wm + i * 16 + quad * 4;
            int n  = nt * 128 + wn + j * 16 + l16;
            if (n < N_) {
                v4f s = *(const v4f*)&TB[3072 + p0];
                v4f t = *(const v4f*)&TB[3456 + p0];
                #pragma unroll
                for (int r2 = 0; r2 < 4; r2++)
                    out[((size_t)b * DIM_ + p0 + r2) * N_ + n] = acc[i][j][r2] * s[r2] + t[r2];
            }
        }
    }
}

// ---------------------------------------------------------------------------
extern "C" void kernel_launch(void* const* d_in, const int* in_sizes, int n_in,
                              void* d_out, int out_size, void* d_ws, size_t ws_size,
                              hipStream_t stream)
{
    const float* x    = (const float*)d_in[0];
    const float* wq   = (const float*)d_in[1];
    const float* bq   = (const float*)d_in[2];
    const float* bnq  = (const float*)d_in[3];
    const float* wk   = (const float*)d_in[4];
    const float* bk   = (const float*)d_in[5];
    const float* bnk  = (const float*)d_in[6];
    const float* wv   = (const float*)d_in[7];
    const float* bv   = (const float*)d_in[8];
    const float* bnv  = (const float*)d_in[9];
    const float* wvl  = (const float*)d_in[10];
    const float* bvl  = (const float*)d_in[11];
    const float* bnvl = (const float*)d_in[12];
    const float* th1w = (const float*)d_in[13];
    const float* th1b = (const float*)d_in[14];
    const float* th2w = (const float*)d_in[15];
    const float* th2b = (const float*)d_in[16];
    const float* wp   = (const float*)d_in[17];
    const float* bp   = (const float*)d_in[18];
    const float* bnp  = (const float*)d_in[19];
    const float* ab   = (const float*)d_in[20];
    const int*   bidx = (const int*)d_in[21];
    float* out = (float*)d_out;

    u16* wsb  = (u16*)d_ws;
    u16* WbI  = wsb + WBI_OFF;
    u16* WpI  = wsb + WPI_OFF;
    u16* qI   = wsb + QI_OFF;
    u16* kI   = wsb + KI_OFF;
    u16* vI   = wsb + VI_OFF;
    u16* vlocI = wsb + VLOC_U16;
    u16* xI   = wsb + TAIL_OFF;   // aliased: xI -> aoI (disjoint lifetimes)
    u16* aoI  = wsb + TAIL_OFF;
    float* TB    = (float*)(wsb + TB_OFF);
    float* abT1  = (float*)(wsb + ABT_OFF);
    float* biasE = (float*)(wsb + BIASE_OFF);

    k_castW<<<dim3(3859), 256, 0, stream>>>(wq, wk, wv, wp, ab, th1w, th1b,
                                            bq, bnq, bk, bnk, bv, bnv, bp, bnp, bvl, bnvl,
                                            WbI, WpI, abT1, TB);
    k_bias<<<dim3((N_ * 8 * N_ + 255) / 256), 256, 0, stream>>>(abT1, bidx, biasE);
    k_castX<<<dim3(4, 6, B_), 256, 0, stream>>>(x, xI);
    k_qkv<<<dim3(2, 12, B_), 256, 0, stream>>>(WbI, xI, TB, qI, kI, vI);
    k_dwconv<<<dim3(16, B_), 256, 0, stream>>>(vI, wvl, TB, vlocI);
    k_attn_av<<<dim3(25, B_), 512, 0, stream>>>(qI, kI, vI, th1w, th2w, th2b,
                                                biasE, vlocI, aoI);
    k_proj<<<dim3(2, 3, B_), 256, 0, stream>>>(WpI, aoI, TB, out);
}

// Round 4
// 251.633 us; speedup vs baseline: 1.1928x; 1.0658x over previous
//
#include <hip/hip_runtime.h>

#define B_     64
#define DIM_   384
#define RES_   14
#define N_     196
#define HEADS_ 8
#define KD_    32
#define D_     128
#define DH_    1024
#define QK_    256
#define CH_    1536
#define EPS_   1e-5f
#define SCALE_ 0.17677669529663687f   // 32^-0.5

typedef unsigned short u16;
typedef unsigned int u32;
typedef short v8s __attribute__((ext_vector_type(8)));
typedef float v4f __attribute__((ext_vector_type(4)));
typedef u16  v4u __attribute__((ext_vector_type(4)));

static __device__ __forceinline__ u16 f2bf(float f) {
    unsigned int u = __builtin_bit_cast(unsigned int, f);
    u = (u + 0x7fffu + ((u >> 16) & 1u)) >> 16;
    return (u16)u;
}
static __device__ __forceinline__ float bf2f(u16 u) {
    unsigned int x = ((unsigned int)u) << 16;
    return __builtin_bit_cast(float, x);
}
static __device__ __forceinline__ u16 f2h(float f) {
    _Float16 h = (_Float16)f;
    return __builtin_bit_cast(u16, h);
}
static __device__ __forceinline__ float h2f(u16 u) {
    return (float)__builtin_bit_cast(_Float16, u);
}

// workspace layout (u16 element offsets)
// GEMM operand images: [kstep][kquad(4)][row(128)][8] = 4096 elems (8KB)/kstep
#define WBI_OFF  0u          // Wb  image: 12 mtiles x 12 ksteps      (589824)
#define WPI_OFF  589824u     // wp  image: 3 mtiles x 32 ksteps       (393216)
#define QI_OFF   983040u     // qT  [B][8][256][32]                   (4194304)
#define KI_OFF   5177344u    // kT  [B][8][256][32]                   (4194304)
#define VI_OFF   9371648u    // v   image: [B][8] x 7 ksteps          (14680064)
#define VLOC_U16 53411840u   // vlocI in aoI image layout             (16777216)
#define TAIL_OFF 79101952u   // union: xI (6291456) / aoI (16777216)
#define TB_OFF   98770944u   // BN tables fp32[5888]
#define BIASE_OFF 98785920u  // biasE [196][8][196] fp32 (614656 u16)

// ---------------------------------------------------------------------------
// barrier-free direct-from-global 128x128 MFMA core. Operands pre-packed in
// fragment order; 2-deep software pipeline, NO LDS, NO __syncthreads.
// ---------------------------------------------------------------------------
template<int KSTEPS>
static __device__ __forceinline__ void gemm_direct(
    const u16* __restrict__ Ag, const u16* __restrict__ Bg,
    v4f acc[4][4], int tid)
{
    const int lane = tid & 63, w = tid >> 6;
    const int wm = (w & 1) * 64, wn = (w >> 1) * 64;
    const int quad = lane >> 4, l16 = lane & 15;
    const u16* pa = Ag + quad * 1024 + (wm + l16) * 8;
    const u16* pb = Bg + quad * 1024 + (wn + l16) * 8;
    v8s a[2][4], b[2][4];
    #pragma unroll
    for (int i = 0; i < 4; i++) {
        a[0][i] = *(const v8s*)(pa + i * 128);
        b[0][i] = *(const v8s*)(pb + i * 128);
    }
    #pragma unroll
    for (int ks = 0; ks < KSTEPS; ks++) {
        const int cur = ks & 1, nxt = cur ^ 1;
        if (ks + 1 < KSTEPS) {
            const u16* qa = pa + (size_t)(ks + 1) * 4096;
            const u16* qb = pb + (size_t)(ks + 1) * 4096;
            #pragma unroll
            for (int i = 0; i < 4; i++) {
                a[nxt][i] = *(const v8s*)(qa + i * 128);
                b[nxt][i] = *(const v8s*)(qb + i * 128);
            }
        }
        #pragma unroll
        for (int i = 0; i < 4; i++)
            #pragma unroll
            for (int j = 0; j < 4; j++)
                acc[i][j] = __builtin_amdgcn_mfma_f32_16x16x32_bf16(a[cur][i], b[cur][j], acc[i][j], 0, 0, 0);
    }
}

// 3-deep variant for long-K latency-exposed GEMMs (k_proj: K=32 steps,
// only ~1.5 blocks/CU so intra-wave pipelining must cover L2 latency).
template<int KSTEPS>
static __device__ __forceinline__ void gemm_direct3(
    const u16* __restrict__ Ag, const u16* __restrict__ Bg,
    v4f acc[4][4], int tid)
{
    const int lane = tid & 63, w = tid >> 6;
    const int wm = (w & 1) * 64, wn = (w >> 1) * 64;
    const int quad = lane >> 4, l16 = lane & 15;
    const u16* pa = Ag + quad * 1024 + (wm + l16) * 8;
    const u16* pb = Bg + quad * 1024 + (wn + l16) * 8;
    v8s a[3][4], b[3][4];
    #pragma unroll
    for (int s = 0; s < 2; s++) {
        #pragma unroll
        for (int i = 0; i < 4; i++) {
            a[s][i] = *(const v8s*)(pa + (size_t)s * 4096 + i * 128);
            b[s][i] = *(const v8s*)(pb + (size_t)s * 4096 + i * 128);
        }
    }
    #pragma unroll
    for (int ks = 0; ks < KSTEPS; ks++) {
        const int cur = ks % 3, nxt = (ks + 2) % 3;
        if (ks + 2 < KSTEPS) {
            const u16* qa = pa + (size_t)(ks + 2) * 4096;
            const u16* qb = pb + (size_t)(ks + 2) * 4096;
            #pragma unroll
            for (int i = 0; i < 4; i++) {
                a[nxt][i] = *(const v8s*)(qa + i * 128);
                b[nxt][i] = *(const v8s*)(qb + i * 128);
            }
        }
        #pragma unroll
        for (int i = 0; i < 4; i++)
            #pragma unroll
            for (int j = 0; j < 4; j++)
                acc[i][j] = __builtin_amdgcn_mfma_f32_16x16x32_bf16(a[cur][i], b[cur][j], acc[i][j], 0, 0, 0);
    }
}

// ---------------------------------------------------------------------------
// k_pre: ALL preprocessing in one launch.
//   blocks [0,1536):        x fp32 -> xI image (LDS transpose)
//   blocks [1536,6588):     weight images + BN tables + biasE (abT1 inlined)
// ---------------------------------------------------------------------------
__global__ __launch_bounds__(256) void k_pre(
    const float* __restrict__ x,
    const float* __restrict__ wq, const float* __restrict__ wk,
    const float* __restrict__ wv, const float* __restrict__ wp,
    const float* __restrict__ ab,
    const float* __restrict__ th1w, const float* __restrict__ th1b,
    const float* __restrict__ bq, const float* __restrict__ bnq,
    const float* __restrict__ bk, const float* __restrict__ bnk,
    const float* __restrict__ bv, const float* __restrict__ bnv,
    const float* __restrict__ bp, const float* __restrict__ bnp,
    const float* __restrict__ bvl, const float* __restrict__ bnvl,
    const int* __restrict__ bidx,
    u16* __restrict__ xI, u16* __restrict__ WbI, u16* __restrict__ WpI,
    float* __restrict__ TB, float* __restrict__ biasE)
{
    __shared__ float T[64][65];
    const int tid = threadIdx.x;
    if (blockIdx.x < 1536) {      // ---- castX ----
        const int t  = blockIdx.x;
        const int n0 = (t & 3) * 64;
        const int k0 = ((t >> 2) % 6) * 64;
        const int b  = t / 24;
        const int c = tid & 63, r4 = tid >> 6;
        #pragma unroll
        for (int i = 0; i < 16; i++) {
            int kr = i * 4 + r4;
            int gn = n0 + c;
            T[kr][c] = (gn < N_) ? x[((size_t)b * DIM_ + k0 + kr) * N_ + gn] : 0.f;
        }
        __syncthreads();
        #pragma unroll
        for (int it = 0; it < 16; it++) {
            int j = it * 256 + tid;
            int kk = j & 63, nn = j >> 6;
            int k = k0 + kk, n = n0 + nn;
            xI[(size_t)b * 98304 + (n >> 7) * 49152 + (k >> 5) * 4096
               + ((k >> 3) & 3) * 1024 + (n & 127) * 8 + (k & 7)] = f2bf(T[kk][nn]);
        }
        return;
    }
    int i = (blockIdx.x - 1536) * 256 + tid;
    if (i < 589824) {           // qkv weight image
        int mt = i / 49152, rem = i % 49152;
        int ks = rem >> 12, r2 = rem & 4095;
        int q = r2 >> 10, row = (r2 >> 3) & 127, e = r2 & 7;
        int c = mt * 128 + row, k = ks * 32 + q * 8 + e;
        float v = (c < 256) ? wq[c * 384 + k]
                : (c < 512) ? wk[(c - 256) * 384 + k]
                            : wv[(size_t)(c - 512) * 384 + k];
        WbI[i] = f2bf(v);
    } else if (i < 983040) {    // proj weight image
        int j = i - 589824;
        int mt = j >> 17, rem = j & 131071;
        int ks = rem >> 12, r2 = rem & 4095;
        int q = r2 >> 10, row = (r2 >> 3) & 127, e = r2 & 7;
        int p = mt * 128 + row, k = ks * 32 + q * 8 + e;
        WpI[j] = f2bf(wp[(size_t)p * 1024 + k]);
    } else if (i < 985984) {    // BN tables
        int j = i - 983040;
        if (j < 256) {
            int c = j;
            float s = bnq[c] * rsqrtf(bnq[768 + c] + EPS_);
            float t = (bq[c] - bnq[512 + c]) * s + bnq[256 + c];
            TB[c] = s * SCALE_; TB[256 + c] = t * SCALE_;
        } else if (j < 512) {
            int c = j - 256;
            float s = bnk[c] * rsqrtf(bnk[768 + c] + EPS_);
            float t = (bk[c] - bnk[512 + c]) * s + bnk[256 + c];
            TB[512 + c] = s; TB[768 + c] = t;
        } else if (j < 1536) {
            int c = j - 512;
            float s = bnv[c] * rsqrtf(bnv[3072 + c] + EPS_);
            float t = (bv[c] - bnv[2048 + c]) * s + bnv[1024 + c];
            TB[1024 + c] = s; TB[2048 + c] = t;
        } else if (j < 1920) {
            int c = j - 1536;
            float s = bnp[c] * rsqrtf(bnp[1152 + c] + EPS_);
            float t = (bp[c] - bnp[768 + c]) * s + bnp[384 + c];
            TB[3072 + c] = s; TB[3456 + c] = t;
        } else {
            int c = j - 1920;
            float s = bnvl[c] * rsqrtf(bnvl[3072 + c] + EPS_);
            float t = (bvl[c] - bnvl[2048 + c]) * s + bnvl[1024 + c];
            TB[3840 + c] = s; TB[4864 + c] = t;
        }
    } else if (i < 1293312) {   // biasE[n][o][m] = th1-folded bias - 5 (abT1 inlined)
        int j = i - 985984;
        int m = j % N_;
        int t = j / N_;
        int o = t & 7;
        int n = t >> 3;
        int idx = bidx[n * N_ + m];
        float a = th1b[o];
        #pragma unroll
        for (int h = 0; h < 8; h++) a += th1w[o * 8 + h] * ab[h * N_ + idx];
        biasE[j] = a - 5.f;
    }
}

// ---------------------------------------------------------------------------
// K1: QKV GEMM (direct core). qI/kI [b][h][256][32] bf16 (q pre-scaled),
// vI image per (b,o), 7 ksteps (n>=196 zero).
// XCD swizzle: 1536 blocks = 8 XCDs x (8 b x 24 tiles).
// ---------------------------------------------------------------------------
__global__ __launch_bounds__(256) void k_qkv(
    const u16* __restrict__ WbI, const u16* __restrict__ xI,
    const float* __restrict__ TB,
    u16* __restrict__ qI, u16* __restrict__ kI, u16* __restrict__ vI)
{
    const int tid = threadIdx.x;
    const int L = blockIdx.x + 2 * (blockIdx.y + 12 * blockIdx.z);
    const int idx = L >> 3;                 // 0..191
    const int b  = (L & 7) * 8 + idx / 24;  // contiguous b-chunk per XCD
    const int r  = idx % 24;
    const int mt = r >> 1, nt = r & 1;
    v4f acc[4][4] = {};
    gemm_direct<12>(WbI + (size_t)mt * 49152,
                    xI + ((size_t)b * 2 + nt) * 49152, acc, tid);

    const int lane = tid & 63, w = tid >> 6;
    const int wm = (w & 1) * 64, wn = (w >> 1) * 64;
    const int quad = lane >> 4, l16 = lane & 15;
    #pragma unroll
    for (int i = 0; i < 4; i++) {
        #pragma unroll
        for (int j = 0; j < 4; j++) {
            int gc = mt * 128 + wm + i * 16 + quad * 4;  // global channel base
            int n  = nt * 128 + wn + j * 16 + l16;       // token (0..255)
            v4f v = acc[i][j];
            if (gc < 256) {            // q
                v4f s = *(const v4f*)&TB[gc];
                v4f t = *(const v4f*)&TB[256 + gc];
                v4u u;
                #pragma unroll
                for (int r2 = 0; r2 < 4; r2++) u[r2] = f2bf(v[r2] * s[r2] + t[r2]);
                *(v4u*)&qI[((size_t)(b * 8 + (gc >> 5)) * 256 + n) * 32 + (gc & 31)] = u;
            } else if (gc < 512) {     // k
                int c = gc - 256;
                v4f s = *(const v4f*)&TB[512 + c];
                v4f t = *(const v4f*)&TB[768 + c];
                v4u u;
                #pragma unroll
                for (int r2 = 0; r2 < 4; r2++) u[r2] = f2bf(v[r2] * s[r2] + t[r2]);
                *(v4u*)&kI[((size_t)(b * 8 + (c >> 5)) * 256 + n) * 32 + (c & 31)] = u;
            } else {                   // v -> image (row = e, col = n as k-dim)
                int c = gc - 512;      // 0..1023
                if (n < 224) {
                    int o = c >> 7, e = c & 127;
                    u16* base = vI + ((size_t)(b * 8 + o) * 7 + (n >> 5)) * 4096
                                + ((n >> 3) & 3) * 1024 + (n & 7);
                    #pragma unroll
                    for (int r2 = 0; r2 < 4; r2++) {
                        u16 outv = 0;
                        if (n < N_) outv = f2bf(v[r2] * TB[1024 + c + r2] + TB[2048 + c + r2]);
                        base[(e + r2) * 8] = outv;
                    }
                }
            }
        }
    }
}

// ---------------------------------------------------------------------------
// K2: depthwise 3x3 conv. Block = 64 channels of one (b,o).
// ---------------------------------------------------------------------------
__global__ __launch_bounds__(256) void k_dwconv(
    const u16* __restrict__ vI, const float* __restrict__ wvl,
    const float* __restrict__ TB, u16* __restrict__ vlocI)
{
    __shared__ u16 V[64 * 230];             // 29440 B
    const int tid = threadIdx.x;
    const int sub = blockIdx.x;             // 0..15: o = sub>>1, half = sub&1
    const int b   = blockIdx.y;
    const int o   = sub >> 1;
    const int e0  = (sub & 1) * 64;
    const u16* img = vI + (size_t)(b * 8 + o) * 28672;

    {
        const int quad = tid >> 6, l = tid & 63;
        #pragma unroll
        for (int i = 0; i < 7; i++) {
            v8s u = *(const v8s*)&img[i * 4096 + quad * 1024 + (e0 + l) * 8];
            const u32* ui = (const u32*)&u;
            int m0 = i * 32 + quad * 8;
            u32* dst = (u32*)&V[l * 230 + m0];
            #pragma unroll
            for (int c = 0; c < 4; c++) dst[c] = ui[c];
        }
    }
    __syncthreads();

    const int e = tid & 63, j = tid >> 6;
    const int cg = sub * 64 + e;
    const int y0 = j * 4;
    const int ny = (j == 3) ? 2 : 4;
    float wgt[9];
    #pragma unroll
    for (int k = 0; k < 9; k++) wgt[k] = wvl[cg * 9 + k];
    const float sc = TB[3840 + cg], sh = TB[4864 + cg];
    u32 po[4][7];

    for (int yi = 0; yi < ny; yi++) {
        int y = y0 + yi;
        float a[3][16];
        #pragma unroll
        for (int dy = 0; dy < 3; dy++) {
            int yy = y + dy - 1;
            a[dy][0] = 0.f; a[dy][15] = 0.f;
            if (yy < 0 || yy > 13) {
                #pragma unroll
                for (int x = 1; x < 15; x++) a[dy][x] = 0.f;
            } else {
                const u16* rp = &V[e * 230 + yy * 14];
                #pragma unroll
                for (int c4 = 0; c4 < 7; c4++) {
                    u32 u = *(const u32*)&rp[c4 * 2];
                    a[dy][1 + 2 * c4] = bf2f((u16)(u & 0xffffu));
                    a[dy][2 + 2 * c4] = bf2f((u16)(u >> 16));
                }
            }
        }
        #pragma unroll
        for (int xp = 0; xp < 7; xp++) {
            u32 pk = 0;
            #pragma unroll
            for (int half = 0; half < 2; half++) {
                int x = 2 * xp + half;
                float s = 0.f;
                #pragma unroll
                for (int dy = 0; dy < 3; dy++)
                    #pragma unroll
                    for (int kx = 0; kx < 3; kx++)
                        s += wgt[dy * 3 + kx] * a[dy][x + kx];
                u16 bv = f2bf(s * sc + sh);
                pk |= ((u32)bv) << (16 * half);
            }
            po[yi][xp] = pk;
        }
    }
    __syncthreads();

    for (int yi = 0; yi < ny; yi++) {
        u32* dst = (u32*)&V[e * 196 + (y0 + yi) * 14];
        #pragma unroll
        for (int xp = 0; xp < 7; xp++) dst[xp] = po[yi][xp];
    }
    __syncthreads();

    for (int it = 0; it < 7; it++) {
        int idx = it * 256 + tid;
        if (idx < 1568) {
            int g = idx / 196, n = idx - g * 196;
            v4u lo, hi;
            #pragma unroll
            for (int r = 0; r < 4; r++) lo[r] = V[(g * 8 + r) * 196 + n];
            #pragma unroll
            for (int r = 0; r < 4; r++) hi[r] = V[(g * 8 + 4 + r) * 196 + n];
            u16* dst = vlocI + ((size_t)(b * 2 + (n >> 7)) * 32 + sub * 2 + (g >> 2)) * 4096
                     + (g & 3) * 1024 + (n & 127) * 8;
            *(v4u*)dst = lo;
            *(v4u*)(dst + 4) = hi;
        }
    }
}

// ---------------------------------------------------------------------------
// K3: FUSED attention + AV + vloc + relu -> aoI. 512 threads / 8 waves,
// QBLK=16: block owns 16 q-rows so EVERY MFMA column in phase A (QK^T) and
// phase C (AV) is live -- half the MFMA issue + fragment loads per unit work
// vs QBLK=8, and half the blocks/barriers. LDS ~59.5 KB -> 2 blocks/CU
// (16 waves, same effective occupancy as before).
// XCD swizzle: 832 blocks = 8 XCDs x (8 b x 13 qt).
// ---------------------------------------------------------------------------
__global__ __launch_bounds__(512) void k_attn_av(
    const u16* __restrict__ qI, const u16* __restrict__ kI,
    const u16* __restrict__ vI,
    const float* __restrict__ th1w,
    const float* __restrict__ th2w, const float* __restrict__ th2b,
    const float* __restrict__ biasE,
    const u16* __restrict__ vlocI, u16* __restrict__ aoI)
{
    __shared__ u16 Sl[8 * 16 * 228];   // [h][q16][m] = 58368 B
    __shared__ float red[128][4];
    __shared__ float invS[128];        // [h*16+q]
    const int tid = threadIdx.x;
    const int w = tid >> 6, lane = tid & 63;
    const int quad = lane >> 4, l16 = lane & 15;
    const int L = blockIdx.x + 13 * blockIdx.y;
    const int idx = L >> 3;                 // 0..103
    const int b  = (L & 7) * 8 + idx / 13;  // contiguous b-chunk per XCD
    const int qt = idx % 13;                // 0..12
    const int n0 = qt * 16;

    // phase A: wave w -> head w. Operand-swapped MFMA: D[m_local][q16].
    // All 16 q columns live; lane packs 4 consecutive m -> one ds_write_b64.
    {
        const int h = w;
        const u16* qb = qI + (size_t)(b * 8 + h) * 8192;
        const u16* kb = kI + (size_t)(b * 8 + h) * 8192;
        v8s qf = *(const v8s*)&qb[(n0 + l16) * 32 + quad * 8];   // B operand (cols)
        #pragma unroll
        for (int mt = 0; mt < 13; mt++) {
            v8s kf = *(const v8s*)&kb[(mt * 16 + l16) * 32 + quad * 8]; // A operand (rows)
            v4f acc = {};
            acc = __builtin_amdgcn_mfma_f32_16x16x32_bf16(kf, qf, acc, 0, 0, 0);
            v4u pk;
            #pragma unroll
            for (int r = 0; r < 4; r++) pk[r] = f2h(acc[r]);
            *(v4u*)&Sl[(h * 16 + l16) * 228 + mt * 16 + quad * 4] = pk;
        }
    }
    __syncthreads();

    // phase B1: thread owns (m-pair, q-quad); all LDS traffic u32, biasE float2
    const int mp  = (tid & 127) * 2;   // 0,2,...,254
    const int qh  = tid >> 7;          // 0..3 -> q = qh*4 + qq
    const bool pvalid = (mp < N_);     // N_=196 even -> pair fully valid/invalid
    for (int qq = 0; qq < 4; qq++) {
        int q = qh * 4 + qq;
        int n = n0 + q;
        if (pvalid && n < N_) {
            const float* bE = biasE + (size_t)n * 1568 + mp;
            float S0[8], S1[8];
            #pragma unroll
            for (int h = 0; h < 8; h++) {
                u32 u = *(const u32*)&Sl[(h * 16 + q) * 228 + mp];
                S0[h] = h2f((u16)(u & 0xffffu));
                S1[h] = h2f((u16)(u >> 16));
            }
            u32 ew[8];
            #pragma unroll
            for (int o = 0; o < 8; o++) {
                float2 bb = *(const float2*)&bE[o * 196];
                float a0 = bb.x, a1 = bb.y;
                #pragma unroll
                for (int h = 0; h < 8; h++) {
                    a0 += th1w[o * 8 + h] * S0[h];
                    a1 += th1w[o * 8 + h] * S1[h];
                }
                ew[o] = (u32)f2h(__expf(a0)) | ((u32)f2h(__expf(a1)) << 16);
            }
            #pragma unroll
            for (int o = 0; o < 8; o++)
                *(u32*)&Sl[(o * 16 + q) * 228 + mp] = ew[o];
        }
    }
    __syncthreads();

    // phase B2: 128 rows x 4 quarters; vectorized u32 LDS reads (m < 196)
    {
        int r = tid >> 2, quarter = tid & 3;
        int mstart = quarter * 48;
        int cnt = (quarter == 3) ? 26 : 24;   // u32 pairs: 3*24 + 26 = 98 -> 196
        const u16* rowp = &Sl[r * 228 + mstart];
        float s = 0.f;
        for (int i = 0; i < cnt; i++) {
            u32 u = *(const u32*)&rowp[i * 2];
            s += h2f((u16)(u & 0xffffu)) + h2f((u16)(u >> 16));
        }
        red[r][quarter] = s;
    }
    __syncthreads();
    if (tid < 128)
        invS[tid] = 1.f / (red[tid][0] + red[tid][1] + red[tid][2] + red[tid][3]);
    __syncthreads();

    // phase B3: scale + TH2 in place (bf16); m-pair u32 traffic
    for (int qq = 0; qq < 4; qq++) {
        int q = qh * 4 + qq;
        bool valid = pvalid && (n0 + q < N_);
        u32 pw[8];
        if (valid) {
            float s0[8], s1[8];
            #pragma unroll
            for (int h = 0; h < 8; h++) {
                u32 u = *(const u32*)&Sl[(h * 16 + q) * 228 + mp];
                float is = invS[h * 16 + q];
                s0[h] = h2f((u16)(u & 0xffffu)) * is;
                s1[h] = h2f((u16)(u >> 16)) * is;
            }
            #pragma unroll
            for (int o = 0; o < 8; o++) {
                float v0 = th2b[o], v1 = th2b[o];
                #pragma unroll
                for (int h = 0; h < 8; h++) {
                    v0 += th2w[o * 8 + h] * s0[h];
                    v1 += th2w[o * 8 + h] * s1[h];
                }
                pw[o] = (u32)f2bf(v0) | ((u32)f2bf(v1) << 16);
            }
        } else {
            #pragma unroll
            for (int o = 0; o < 8; o++) pw[o] = 0;
        }
        if (mp < 224) {
            #pragma unroll
            for (int o = 0; o < 8; o++)
                *(u32*)&Sl[(o * 16 + q) * 228 + mp] = pw[o];
        }
    }
    __syncthreads();

    // phase C: AV. Wave w handles o = w; all 16 output columns live.
    {
        const int half_ = n0 >> 7;
        const int row0 = n0 & 127;
        const int n = n0 + l16;
        const bool act = (n < N_);
        const int o = w;
        const u16* vb = vI + (size_t)(b * 8 + o) * 28672;
        const u16* prow = &Sl[(o * 16 + l16) * 228];
        __builtin_amdgcn_s_setprio(1);
        #pragma unroll
        for (int eh = 0; eh < 2; eh++) {       // 2 e-halves of 64
            v4f acc[4] = {};
            v8s a[2][4];
            const u16* ab0 = vb + quad * 1024 + (eh * 64 + l16) * 8;
            #pragma unroll
            for (int e = 0; e < 4; e++) a[0][e] = *(const v8s*)(ab0 + e * 128);
            #pragma unroll
            for (int ks = 0; ks < 7; ks++) {
                const int cur = ks & 1, nxt = cur ^ 1;
                if (ks < 6) {
                    const u16* an = ab0 + (size_t)(ks + 1) * 4096;
                    #pragma unroll
                    for (int e = 0; e < 4; e++) a[nxt][e] = *(const v8s*)(an + e * 128);
                }
                v8s bfr = *(const v8s*)&prow[ks * 32 + quad * 8];
                #pragma unroll
                for (int e = 0; e < 4; e++)
                    acc[e] = __builtin_amdgcn_mfma_f32_16x16x32_bf16(a[cur][e], bfr, acc[e], 0, 0, 0);
            }
            if (act) {
                #pragma unroll
                for (int e = 0; e < 4; e++) {
                    const int c0 = o * 128 + (eh * 4 + e) * 16 + quad * 4;
                    const size_t ioff = ((size_t)(b * 2 + half_) * 32 + (c0 >> 5)) * 4096
                                      + ((c0 >> 3) & 3) * 1024 + (size_t)(row0 + l16) * 8 + (c0 & 7);
                    v4u lv = *(const v4u*)&vlocI[ioff];
                    v4u u;
                    #pragma unroll
                    for (int r = 0; r < 4; r++)
                        u[r] = f2bf(fmaxf(acc[e][r] + bf2f(lv[r]), 0.f));
                    *(v4u*)&aoI[ioff] = u;
                }
            }
        }
        __builtin_amdgcn_s_setprio(0);
    }
}

// ---------------------------------------------------------------------------
// K6: projection GEMM (3-deep direct core, K=1024) + BN -> out fp32
// XCD swizzle: 384 blocks = 8 XCDs x (8 b x 6 tiles).
// ---------------------------------------------------------------------------
__global__ __launch_bounds__(256) void k_proj(
    const u16* __restrict__ WpI, const u16* __restrict__ aoI,
    const float* __restrict__ TB, float* __restrict__ out)
{
    const int tid = threadIdx.x;
    const int L = blockIdx.x + 2 * (blockIdx.y + 3 * blockIdx.z);
    const int idx = L >> 3;                 // 0..47
    const int b  = (L & 7) * 8 + idx / 6;   // contiguous b-chunk per XCD
    const int r  = idx % 6;
    const int mt = r >> 1, nt = r & 1;
    v4f acc[4][4] = {};
    gemm_direct3<32>(WpI + (size_t)mt * 131072,
                     aoI + ((size_t)b * 2 + nt) * 131072, acc, tid);

    const int lane = tid & 63, w = tid >> 6;
    const int wm = (w & 1) * 64, wn = (w >> 1) * 64;
    const int quad = lane >> 4, l16 = lane & 15;
    #pragma unroll
    for (int i = 0; i < 4; i++) {
        #pragma unroll
        for (int j = 0; j < 4; j++) {
            int p0 = mt * 128 + wm + i * 16 + quad * 4;
            int n  = nt * 128 + wn + j * 16 + l16;
            if (n < N_) {
                v4f s = *(const v4f*)&TB[3072 + p0];
                v4f t = *(const v4f*)&TB[3456 + p0];
                #pragma unroll
                for (int r2 = 0; r2 < 4; r2++)
                    out[((size_t)b * DIM_ + p0 + r2) * N_ + n] = acc[i][j][r2] * s[r2] + t[r2];
            }
        }
    }
}

// ---------------------------------------------------------------------------
extern "C" void kernel_launch(void* const* d_in, const int* in_sizes, int n_in,
                              void* d_out, int out_size, void* d_ws, size_t ws_size,
                              hipStream_t stream)
{
    const float* x    = (const float*)d_in[0];
    const float* wq   = (const float*)d_in[1];
    const float* bq   = (const float*)d_in[2];
    const float* bnq  = (const float*)d_in[3];
    const float* wk   = (const float*)d_in[4];
    const float* bk   = (const float*)d_in[5];
    const float* bnk  = (const float*)d_in[6];
    const float* wv   = (const float*)d_in[7];
    const float* bv   = (const float*)d_in[8];
    const float* bnv  = (const float*)d_in[9];
    const float* wvl  = (const float*)d_in[10];
    const float* bvl  = (const float*)d_in[11];
    const float* bnvl = (const float*)d_in[12];
    const float* th1w = (const float*)d_in[13];
    const float* th1b = (const float*)d_in[14];
    const float* th2w = (const float*)d_in[15];
    const float* th2b = (const float*)d_in[16];
    const float* wp   = (const float*)d_in[17];
    const float* bp   = (const float*)d_in[18];
    const float* bnp  = (const float*)d_in[19];
    const float* ab   = (const float*)d_in[20];
    const int*   bidx = (const int*)d_in[21];
    float* out = (float*)d_out;

    u16* wsb  = (u16*)d_ws;
    u16* WbI  = wsb + WBI_OFF;
    u16* WpI  = wsb + WPI_OFF;
    u16* qI   = wsb + QI_OFF;
    u16* kI   = wsb + KI_OFF;
    u16* vI   = wsb + VI_OFF;
    u16* vlocI = wsb + VLOC_U16;
    u16* xI   = wsb + TAIL_OFF;   // aliased: xI -> aoI (disjoint lifetimes)
    u16* aoI  = wsb + TAIL_OFF;
    float* TB    = (float*)(wsb + TB_OFF);
    float* biasE = (float*)(wsb + BIASE_OFF);

    k_pre<<<dim3(6588), 256, 0, stream>>>(x, wq, wk, wv, wp, ab, th1w, th1b,
                                          bq, bnq, bk, bnk, bv, bnv, bp, bnp, bvl, bnvl,
                                          bidx, xI, WbI, WpI, TB, biasE);
    k_qkv<<<dim3(2, 12, B_), 256, 0, stream>>>(WbI, xI, TB, qI, kI, vI);
    k_dwconv<<<dim3(16, B_), 256, 0, stream>>>(vI, wvl, TB, vlocI);
    k_attn_av<<<dim3(13, B_), 512, 0, stream>>>(qI, kI, vI, th1w, th2w, th2b,
                                                biasE, vlocI, aoI);
    k_proj<<<dim3(2, 3, B_), 256, 0, stream>>>(WpI, aoI, TB, out);
}

// Round 5
// 249.779 us; speedup vs baseline: 1.2017x; 1.0074x over previous
//
#include <hip/hip_runtime.h>

#define B_     64
#define DIM_   384
#define RES_   14
#define N_     196
#define HEADS_ 8
#define KD_    32
#define D_     128
#define DH_    1024
#define QK_    256
#define CH_    1536
#define EPS_   1e-5f
#define SCALE_ 0.17677669529663687f   // 32^-0.5

typedef unsigned short u16;
typedef unsigned int u32;
typedef short v8s __attribute__((ext_vector_type(8)));
typedef float v4f __attribute__((ext_vector_type(4)));
typedef u16  v4u __attribute__((ext_vector_type(4)));

static __device__ __forceinline__ u16 f2bf(float f) {
    unsigned int u = __builtin_bit_cast(unsigned int, f);
    u = (u + 0x7fffu + ((u >> 16) & 1u)) >> 16;
    return (u16)u;
}
static __device__ __forceinline__ float bf2f(u16 u) {
    unsigned int x = ((unsigned int)u) << 16;
    return __builtin_bit_cast(float, x);
}
static __device__ __forceinline__ u16 f2h(float f) {
    _Float16 h = (_Float16)f;
    return __builtin_bit_cast(u16, h);
}
static __device__ __forceinline__ float h2f(u16 u) {
    return (float)__builtin_bit_cast(_Float16, u);
}

// workspace layout (u16 element offsets)
// GEMM operand images: [kstep][kquad(4)][row(128)][8] = 4096 elems (8KB)/kstep
#define WBI_OFF  0u          // Wb  image: 12 mtiles x 12 ksteps      (589824)
#define WPI_OFF  589824u     // wp  image: 3 mtiles x 32 ksteps       (393216)
#define QI_OFF   983040u     // qT  [B][8][256][32]                   (4194304)
#define KI_OFF   5177344u    // kT  [B][8][256][32]                   (4194304)
#define VI_OFF   9371648u    // v   image: [B][8] x 7 ksteps          (14680064)
#define VLOC_U16 53411840u   // vlocI in aoI image layout             (16777216)
#define TAIL_OFF 79101952u   // union: xI (6291456) / aoI (16777216)
#define TB_OFF   98770944u   // BN tables fp32[5888]
#define BIASE_OFF 98785920u  // biasE [196][8][196] fp32 (614656 u16)

// ---------------------------------------------------------------------------
// barrier-free direct-from-global 128x128 MFMA core. Operands pre-packed in
// fragment order; 2-deep software pipeline, NO LDS, NO __syncthreads.
// ---------------------------------------------------------------------------
template<int KSTEPS>
static __device__ __forceinline__ void gemm_direct(
    const u16* __restrict__ Ag, const u16* __restrict__ Bg,
    v4f acc[4][4], int tid)
{
    const int lane = tid & 63, w = tid >> 6;
    const int wm = (w & 1) * 64, wn = (w >> 1) * 64;
    const int quad = lane >> 4, l16 = lane & 15;
    const u16* pa = Ag + quad * 1024 + (wm + l16) * 8;
    const u16* pb = Bg + quad * 1024 + (wn + l16) * 8;
    v8s a[2][4], b[2][4];
    #pragma unroll
    for (int i = 0; i < 4; i++) {
        a[0][i] = *(const v8s*)(pa + i * 128);
        b[0][i] = *(const v8s*)(pb + i * 128);
    }
    #pragma unroll
    for (int ks = 0; ks < KSTEPS; ks++) {
        const int cur = ks & 1, nxt = cur ^ 1;
        if (ks + 1 < KSTEPS) {
            const u16* qa = pa + (size_t)(ks + 1) * 4096;
            const u16* qb = pb + (size_t)(ks + 1) * 4096;
            #pragma unroll
            for (int i = 0; i < 4; i++) {
                a[nxt][i] = *(const v8s*)(qa + i * 128);
                b[nxt][i] = *(const v8s*)(qb + i * 128);
            }
        }
        #pragma unroll
        for (int i = 0; i < 4; i++)
            #pragma unroll
            for (int j = 0; j < 4; j++)
                acc[i][j] = __builtin_amdgcn_mfma_f32_16x16x32_bf16(a[cur][i], b[cur][j], acc[i][j], 0, 0, 0);
    }
}

// 3-deep variant for long-K latency-exposed GEMMs (k_proj: K=32 steps,
// only ~1.5 blocks/CU so intra-wave pipelining must cover L2 latency).
template<int KSTEPS>
static __device__ __forceinline__ void gemm_direct3(
    const u16* __restrict__ Ag, const u16* __restrict__ Bg,
    v4f acc[4][4], int tid)
{
    const int lane = tid & 63, w = tid >> 6;
    const int wm = (w & 1) * 64, wn = (w >> 1) * 64;
    const int quad = lane >> 4, l16 = lane & 15;
    const u16* pa = Ag + quad * 1024 + (wm + l16) * 8;
    const u16* pb = Bg + quad * 1024 + (wn + l16) * 8;
    v8s a[3][4], b[3][4];
    #pragma unroll
    for (int s = 0; s < 2; s++) {
        #pragma unroll
        for (int i = 0; i < 4; i++) {
            a[s][i] = *(const v8s*)(pa + (size_t)s * 4096 + i * 128);
            b[s][i] = *(const v8s*)(pb + (size_t)s * 4096 + i * 128);
        }
    }
    #pragma unroll
    for (int ks = 0; ks < KSTEPS; ks++) {
        const int cur = ks % 3, nxt = (ks + 2) % 3;
        if (ks + 2 < KSTEPS) {
            const u16* qa = pa + (size_t)(ks + 2) * 4096;
            const u16* qb = pb + (size_t)(ks + 2) * 4096;
            #pragma unroll
            for (int i = 0; i < 4; i++) {
                a[nxt][i] = *(const v8s*)(qa + i * 128);
                b[nxt][i] = *(const v8s*)(qb + i * 128);
            }
        }
        #pragma unroll
        for (int i = 0; i < 4; i++)
            #pragma unroll
            for (int j = 0; j < 4; j++)
                acc[i][j] = __builtin_amdgcn_mfma_f32_16x16x32_bf16(a[cur][i], b[cur][j], acc[i][j], 0, 0, 0);
    }
}

// ---------------------------------------------------------------------------
// k_pre: ALL preprocessing in one launch.
//   blocks [0,1536):        x fp32 -> xI image (LDS transpose)
//   blocks [1536,6588):     weight images + BN tables + biasE (abT1 inlined)
// ---------------------------------------------------------------------------
__global__ __launch_bounds__(256) void k_pre(
    const float* __restrict__ x,
    const float* __restrict__ wq, const float* __restrict__ wk,
    const float* __restrict__ wv, const float* __restrict__ wp,
    const float* __restrict__ ab,
    const float* __restrict__ th1w, const float* __restrict__ th1b,
    const float* __restrict__ bq, const float* __restrict__ bnq,
    const float* __restrict__ bk, const float* __restrict__ bnk,
    const float* __restrict__ bv, const float* __restrict__ bnv,
    const float* __restrict__ bp, const float* __restrict__ bnp,
    const float* __restrict__ bvl, const float* __restrict__ bnvl,
    const int* __restrict__ bidx,
    u16* __restrict__ xI, u16* __restrict__ WbI, u16* __restrict__ WpI,
    float* __restrict__ TB, float* __restrict__ biasE)
{
    __shared__ float T[64][65];
    const int tid = threadIdx.x;
    if (blockIdx.x < 1536) {      // ---- castX ----
        const int t  = blockIdx.x;
        const int n0 = (t & 3) * 64;
        const int k0 = ((t >> 2) % 6) * 64;
        const int b  = t / 24;
        const int c = tid & 63, r4 = tid >> 6;
        #pragma unroll
        for (int i = 0; i < 16; i++) {
            int kr = i * 4 + r4;
            int gn = n0 + c;
            T[kr][c] = (gn < N_) ? x[((size_t)b * DIM_ + k0 + kr) * N_ + gn] : 0.f;
        }
        __syncthreads();
        #pragma unroll
        for (int it = 0; it < 16; it++) {
            int j = it * 256 + tid;
            int kk = j & 63, nn = j >> 6;
            int k = k0 + kk, n = n0 + nn;
            xI[(size_t)b * 98304 + (n >> 7) * 49152 + (k >> 5) * 4096
               + ((k >> 3) & 3) * 1024 + (n & 127) * 8 + (k & 7)] = f2bf(T[kk][nn]);
        }
        return;
    }
    int i = (blockIdx.x - 1536) * 256 + tid;
    if (i < 589824) {           // qkv weight image
        int mt = i / 49152, rem = i % 49152;
        int ks = rem >> 12, r2 = rem & 4095;
        int q = r2 >> 10, row = (r2 >> 3) & 127, e = r2 & 7;
        int c = mt * 128 + row, k = ks * 32 + q * 8 + e;
        float v = (c < 256) ? wq[c * 384 + k]
                : (c < 512) ? wk[(c - 256) * 384 + k]
                            : wv[(size_t)(c - 512) * 384 + k];
        WbI[i] = f2bf(v);
    } else if (i < 983040) {    // proj weight image
        int j = i - 589824;
        int mt = j >> 17, rem = j & 131071;
        int ks = rem >> 12, r2 = rem & 4095;
        int q = r2 >> 10, row = (r2 >> 3) & 127, e = r2 & 7;
        int p = mt * 128 + row, k = ks * 32 + q * 8 + e;
        WpI[j] = f2bf(wp[(size_t)p * 1024 + k]);
    } else if (i < 985984) {    // BN tables
        int j = i - 983040;
        if (j < 256) {
            int c = j;
            float s = bnq[c] * rsqrtf(bnq[768 + c] + EPS_);
            float t = (bq[c] - bnq[512 + c]) * s + bnq[256 + c];
            TB[c] = s * SCALE_; TB[256 + c] = t * SCALE_;
        } else if (j < 512) {
            int c = j - 256;
            float s = bnk[c] * rsqrtf(bnk[768 + c] + EPS_);
            float t = (bk[c] - bnk[512 + c]) * s + bnk[256 + c];
            TB[512 + c] = s; TB[768 + c] = t;
        } else if (j < 1536) {
            int c = j - 512;
            float s = bnv[c] * rsqrtf(bnv[3072 + c] + EPS_);
            float t = (bv[c] - bnv[2048 + c]) * s + bnv[1024 + c];
            TB[1024 + c] = s; TB[2048 + c] = t;
        } else if (j < 1920) {
            int c = j - 1536;
            float s = bnp[c] * rsqrtf(bnp[1152 + c] + EPS_);
            float t = (bp[c] - bnp[768 + c]) * s + bnp[384 + c];
            TB[3072 + c] = s; TB[3456 + c] = t;
        } else {
            int c = j - 1920;
            float s = bnvl[c] * rsqrtf(bnvl[3072 + c] + EPS_);
            float t = (bvl[c] - bnvl[2048 + c]) * s + bnvl[1024 + c];
            TB[3840 + c] = s; TB[4864 + c] = t;
        }
    } else if (i < 1293312) {   // biasE[n][o][m] = th1-folded bias - 5 (abT1 inlined)
        int j = i - 985984;
        int m = j % N_;
        int t = j / N_;
        int o = t & 7;
        int n = t >> 3;
        int idx = bidx[n * N_ + m];
        float a = th1b[o];
        #pragma unroll
        for (int h = 0; h < 8; h++) a += th1w[o * 8 + h] * ab[h * N_ + idx];
        biasE[j] = a - 5.f;
    }
}

// ---------------------------------------------------------------------------
// K1: QKV GEMM (direct core). qI/kI [b][h][256][32] bf16 (q pre-scaled),
// vI image per (b,o), 7 ksteps (n>=196 zero).
// XCD swizzle: 1536 blocks = 8 XCDs x (8 b x 24 tiles).
// ---------------------------------------------------------------------------
__global__ __launch_bounds__(256) void k_qkv(
    const u16* __restrict__ WbI, const u16* __restrict__ xI,
    const float* __restrict__ TB,
    u16* __restrict__ qI, u16* __restrict__ kI, u16* __restrict__ vI)
{
    const int tid = threadIdx.x;
    const int L = blockIdx.x + 2 * (blockIdx.y + 12 * blockIdx.z);
    const int idx = L >> 3;                 // 0..191
    const int b  = (L & 7) * 8 + idx / 24;  // contiguous b-chunk per XCD
    const int r  = idx % 24;
    const int mt = r >> 1, nt = r & 1;
    v4f acc[4][4] = {};
    gemm_direct<12>(WbI + (size_t)mt * 49152,
                    xI + ((size_t)b * 2 + nt) * 49152, acc, tid);

    const int lane = tid & 63, w = tid >> 6;
    const int wm = (w & 1) * 64, wn = (w >> 1) * 64;
    const int quad = lane >> 4, l16 = lane & 15;
    #pragma unroll
    for (int i = 0; i < 4; i++) {
        #pragma unroll
        for (int j = 0; j < 4; j++) {
            int gc = mt * 128 + wm + i * 16 + quad * 4;  // global channel base
            int n  = nt * 128 + wn + j * 16 + l16;       // token (0..255)
            v4f v = acc[i][j];
            if (gc < 256) {            // q
                v4f s = *(const v4f*)&TB[gc];
                v4f t = *(const v4f*)&TB[256 + gc];
                v4u u;
                #pragma unroll
                for (int r2 = 0; r2 < 4; r2++) u[r2] = f2bf(v[r2] * s[r2] + t[r2]);
                *(v4u*)&qI[((size_t)(b * 8 + (gc >> 5)) * 256 + n) * 32 + (gc & 31)] = u;
            } else if (gc < 512) {     // k
                int c = gc - 256;
                v4f s = *(const v4f*)&TB[512 + c];
                v4f t = *(const v4f*)&TB[768 + c];
                v4u u;
                #pragma unroll
                for (int r2 = 0; r2 < 4; r2++) u[r2] = f2bf(v[r2] * s[r2] + t[r2]);
                *(v4u*)&kI[((size_t)(b * 8 + (c >> 5)) * 256 + n) * 32 + (c & 31)] = u;
            } else {                   // v -> image (row = e, col = n as k-dim)
                int c = gc - 512;      // 0..1023
                if (n < 224) {
                    int o = c >> 7, e = c & 127;
                    u16* base = vI + ((size_t)(b * 8 + o) * 7 + (n >> 5)) * 4096
                                + ((n >> 3) & 3) * 1024 + (n & 7);
                    #pragma unroll
                    for (int r2 = 0; r2 < 4; r2++) {
                        u16 outv = 0;
                        if (n < N_) outv = f2bf(v[r2] * TB[1024 + c + r2] + TB[2048 + c + r2]);
                        base[(e + r2) * 8] = outv;
                    }
                }
            }
        }
    }
}

// ---------------------------------------------------------------------------
// K2: depthwise 3x3 conv. Block = 64 channels of one (b,o).
// ---------------------------------------------------------------------------
__global__ __launch_bounds__(256) void k_dwconv(
    const u16* __restrict__ vI, const float* __restrict__ wvl,
    const float* __restrict__ TB, u16* __restrict__ vlocI)
{
    __shared__ u16 V[64 * 230];             // 29440 B
    const int tid = threadIdx.x;
    const int sub = blockIdx.x;             // 0..15: o = sub>>1, half = sub&1
    const int b   = blockIdx.y;
    const int o   = sub >> 1;
    const int e0  = (sub & 1) * 64;
    const u16* img = vI + (size_t)(b * 8 + o) * 28672;

    {
        const int quad = tid >> 6, l = tid & 63;
        #pragma unroll
        for (int i = 0; i < 7; i++) {
            v8s u = *(const v8s*)&img[i * 4096 + quad * 1024 + (e0 + l) * 8];
            const u32* ui = (const u32*)&u;
            int m0 = i * 32 + quad * 8;
            u32* dst = (u32*)&V[l * 230 + m0];
            #pragma unroll
            for (int c = 0; c < 4; c++) dst[c] = ui[c];
        }
    }
    __syncthreads();

    const int e = tid & 63, j = tid >> 6;
    const int cg = sub * 64 + e;
    const int y0 = j * 4;
    const int ny = (j == 3) ? 2 : 4;
    float wgt[9];
    #pragma unroll
    for (int k = 0; k < 9; k++) wgt[k] = wvl[cg * 9 + k];
    const float sc = TB[3840 + cg], sh = TB[4864 + cg];
    u32 po[4][7];

    for (int yi = 0; yi < ny; yi++) {
        int y = y0 + yi;
        float a[3][16];
        #pragma unroll
        for (int dy = 0; dy < 3; dy++) {
            int yy = y + dy - 1;
            a[dy][0] = 0.f; a[dy][15] = 0.f;
            if (yy < 0 || yy > 13) {
                #pragma unroll
                for (int x = 1; x < 15; x++) a[dy][x] = 0.f;
            } else {
                const u16* rp = &V[e * 230 + yy * 14];
                #pragma unroll
                for (int c4 = 0; c4 < 7; c4++) {
                    u32 u = *(const u32*)&rp[c4 * 2];
                    a[dy][1 + 2 * c4] = bf2f((u16)(u & 0xffffu));
                    a[dy][2 + 2 * c4] = bf2f((u16)(u >> 16));
                }
            }
        }
        #pragma unroll
        for (int xp = 0; xp < 7; xp++) {
            u32 pk = 0;
            #pragma unroll
            for (int half = 0; half < 2; half++) {
                int x = 2 * xp + half;
                float s = 0.f;
                #pragma unroll
                for (int dy = 0; dy < 3; dy++)
                    #pragma unroll
                    for (int kx = 0; kx < 3; kx++)
                        s += wgt[dy * 3 + kx] * a[dy][x + kx];
                u16 bv = f2bf(s * sc + sh);
                pk |= ((u32)bv) << (16 * half);
            }
            po[yi][xp] = pk;
        }
    }
    __syncthreads();

    for (int yi = 0; yi < ny; yi++) {
        u32* dst = (u32*)&V[e * 196 + (y0 + yi) * 14];
        #pragma unroll
        for (int xp = 0; xp < 7; xp++) dst[xp] = po[yi][xp];
    }
    __syncthreads();

    for (int it = 0; it < 7; it++) {
        int idx = it * 256 + tid;
        if (idx < 1568) {
            int g = idx / 196, n = idx - g * 196;
            v4u lo, hi;
            #pragma unroll
            for (int r = 0; r < 4; r++) lo[r] = V[(g * 8 + r) * 196 + n];
            #pragma unroll
            for (int r = 0; r < 4; r++) hi[r] = V[(g * 8 + 4 + r) * 196 + n];
            u16* dst = vlocI + ((size_t)(b * 2 + (n >> 7)) * 32 + sub * 2 + (g >> 2)) * 4096
                     + (g & 3) * 1024 + (n & 127) * 8;
            *(v4u*)dst = lo;
            *(v4u*)(dst + 4) = hi;
        }
    }
}

// ---------------------------------------------------------------------------
// K3: FUSED attention + AV + vloc + relu -> aoI. 512 threads / 8 waves,
// QBLK=16. LDS cut to ~53.8 KB (Sl stride 228 -> 200) so THREE blocks fit
// per CU (24 waves, 75% cap) instead of two -- the round-4 counters showed
// occupancy 28% was the binding constraint. m in [196,200) zeroed by B3;
// phase C's ks=6 fragments for quad>=1 (m>=200, all zero) read a 16-B
// shared zero fragment. __launch_bounds__(512,6) caps VGPR at 85.
// XCD swizzle: 832 blocks = 8 XCDs x (8 b x 13 qt).
// ---------------------------------------------------------------------------
#define SLS 200   // Sl stride (u16 elems); %4==0 for b64/b128 alignment
__global__ __launch_bounds__(512, 6) void k_attn_av(
    const u16* __restrict__ qI, const u16* __restrict__ kI,
    const u16* __restrict__ vI,
    const float* __restrict__ th1w,
    const float* __restrict__ th2w, const float* __restrict__ th2b,
    const float* __restrict__ biasE,
    const u16* __restrict__ vlocI, u16* __restrict__ aoI)
{
    __shared__ u16 Sl[8 * 16 * SLS];   // [h][q16][m<200] = 51200 B
    __shared__ float red[128][4];
    __shared__ float invS[128];        // [h*16+q]
    __shared__ __attribute__((aligned(16))) u16 Zf[8];   // zero fragment
    const int tid = threadIdx.x;
    const int w = tid >> 6, lane = tid & 63;
    const int quad = lane >> 4, l16 = lane & 15;
    const int L = blockIdx.x + 13 * blockIdx.y;
    const int idx = L >> 3;                 // 0..103
    const int b  = (L & 7) * 8 + idx / 13;  // contiguous b-chunk per XCD
    const int qt = idx % 13;                // 0..12
    const int n0 = qt * 16;
    if (tid < 8) Zf[tid] = 0;

    // phase A: wave w -> head w. Operand-swapped MFMA: D[m_local][q16].
    // All 16 q columns live; lane packs 4 consecutive m -> one ds_write_b64.
    // mt=12, quad>=2 (m in [200,208)) is never read -> skip the write.
    {
        const int h = w;
        const u16* qb = qI + (size_t)(b * 8 + h) * 8192;
        const u16* kb = kI + (size_t)(b * 8 + h) * 8192;
        v8s qf = *(const v8s*)&qb[(n0 + l16) * 32 + quad * 8];   // B operand (cols)
        #pragma unroll
        for (int mt = 0; mt < 13; mt++) {
            v8s kf = *(const v8s*)&kb[(mt * 16 + l16) * 32 + quad * 8]; // A operand (rows)
            v4f acc = {};
            acc = __builtin_amdgcn_mfma_f32_16x16x32_bf16(kf, qf, acc, 0, 0, 0);
            if (mt < 12 || quad < 2) {
                v4u pk;
                #pragma unroll
                for (int r = 0; r < 4; r++) pk[r] = f2h(acc[r]);
                *(v4u*)&Sl[(h * 16 + l16) * SLS + mt * 16 + quad * 4] = pk;
            }
        }
    }
    __syncthreads();

    // phase B1: thread owns (m-pair, q-quad); all LDS traffic u32, biasE float2
    const int mp  = (tid & 127) * 2;   // 0,2,...,254
    const int qh  = tid >> 7;          // 0..3 -> q = qh*4 + qq
    const bool pvalid = (mp < N_);     // N_=196 even -> pair fully valid/invalid
    for (int qq = 0; qq < 4; qq++) {
        int q = qh * 4 + qq;
        int n = n0 + q;
        if (pvalid && n < N_) {
            const float* bE = biasE + (size_t)n * 1568 + mp;
            float S0[8], S1[8];
            #pragma unroll
            for (int h = 0; h < 8; h++) {
                u32 u = *(const u32*)&Sl[(h * 16 + q) * SLS + mp];
                S0[h] = h2f((u16)(u & 0xffffu));
                S1[h] = h2f((u16)(u >> 16));
            }
            u32 ew[8];
            #pragma unroll
            for (int o = 0; o < 8; o++) {
                float2 bb = *(const float2*)&bE[o * 196];
                float a0 = bb.x, a1 = bb.y;
                #pragma unroll
                for (int h = 0; h < 8; h++) {
                    a0 += th1w[o * 8 + h] * S0[h];
                    a1 += th1w[o * 8 + h] * S1[h];
                }
                ew[o] = (u32)f2h(__expf(a0)) | ((u32)f2h(__expf(a1)) << 16);
            }
            #pragma unroll
            for (int o = 0; o < 8; o++)
                *(u32*)&Sl[(o * 16 + q) * SLS + mp] = ew[o];
        }
    }
    __syncthreads();

    // phase B2: 128 rows x 4 quarters; vectorized u32 LDS reads (m < 196)
    {
        int r = tid >> 2, quarter = tid & 3;
        int mstart = quarter * 48;
        int cnt = (quarter == 3) ? 26 : 24;   // u32 pairs: 3*24 + 26 = 98 -> 196
        const u16* rowp = &Sl[r * SLS + mstart];
        float s = 0.f;
        for (int i = 0; i < cnt; i++) {
            u32 u = *(const u32*)&rowp[i * 2];
            s += h2f((u16)(u & 0xffffu)) + h2f((u16)(u >> 16));
        }
        red[r][quarter] = s;
    }
    __syncthreads();
    if (tid < 128)
        invS[tid] = 1.f / (red[tid][0] + red[tid][1] + red[tid][2] + red[tid][3]);
    __syncthreads();

    // phase B3: scale + TH2 in place (bf16); m-pair u32 traffic; zero m<200
    for (int qq = 0; qq < 4; qq++) {
        int q = qh * 4 + qq;
        bool valid = pvalid && (n0 + q < N_);
        u32 pw[8];
        if (valid) {
            float s0[8], s1[8];
            #pragma unroll
            for (int h = 0; h < 8; h++) {
                u32 u = *(const u32*)&Sl[(h * 16 + q) * SLS + mp];
                float is = invS[h * 16 + q];
                s0[h] = h2f((u16)(u & 0xffffu)) * is;
                s1[h] = h2f((u16)(u >> 16)) * is;
            }
            #pragma unroll
            for (int o = 0; o < 8; o++) {
                float v0 = th2b[o], v1 = th2b[o];
                #pragma unroll
                for (int h = 0; h < 8; h++) {
                    v0 += th2w[o * 8 + h] * s0[h];
                    v1 += th2w[o * 8 + h] * s1[h];
                }
                pw[o] = (u32)f2bf(v0) | ((u32)f2bf(v1) << 16);
            }
        } else {
            #pragma unroll
            for (int o = 0; o < 8; o++) pw[o] = 0;
        }
        if (mp < SLS) {
            #pragma unroll
            for (int o = 0; o < 8; o++)
                *(u32*)&Sl[(o * 16 + q) * SLS + mp] = pw[o];
        }
    }

    // pre-issue phase C's first V fragments (pure global, no LDS dependency);
    // the barrier's vmcnt drain completes them exactly when C starts.
    const int o = w;
    const u16* vb = vI + (size_t)(b * 8 + o) * 28672;
    v8s a0pre[4];
    {
        const u16* ab00 = vb + quad * 1024 + l16 * 8;   // eh=0 base
        #pragma unroll
        for (int e = 0; e < 4; e++) a0pre[e] = *(const v8s*)(ab00 + e * 128);
    }
    __syncthreads();

    // phase C: AV. Wave w handles o = w; all 16 output columns live.
    // P fragments: ks<6 and (ks=6,quad=0) from Sl; (ks=6,quad>=1) are the
    // all-zero m>=200 region -> read the shared zero fragment instead.
    {
        const int half_ = n0 >> 7;
        const int row0 = n0 & 127;
        const int n = n0 + l16;
        const bool act = (n < N_);
        const u16* prow = &Sl[(o * 16 + l16) * SLS];
        __builtin_amdgcn_s_setprio(1);
        #pragma unroll
        for (int eh = 0; eh < 2; eh++) {       // 2 e-halves of 64
            v4f acc[4] = {};
            v8s a[2][4];
            const u16* ab0 = vb + quad * 1024 + (eh * 64 + l16) * 8;
            if (eh == 0) {
                #pragma unroll
                for (int e = 0; e < 4; e++) a[0][e] = a0pre[e];
            } else {
                #pragma unroll
                for (int e = 0; e < 4; e++) a[0][e] = *(const v8s*)(ab0 + e * 128);
            }
            #pragma unroll
            for (int ks = 0; ks < 7; ks++) {
                const int cur = ks & 1, nxt = cur ^ 1;
                if (ks < 6) {
                    const u16* an = ab0 + (size_t)(ks + 1) * 4096;
                    #pragma unroll
                    for (int e = 0; e < 4; e++) a[nxt][e] = *(const v8s*)(an + e * 128);
                }
                const u16* psrc = (ks == 6 && quad != 0) ? &Zf[0]
                                                         : &prow[ks * 32 + quad * 8];
                v8s bfr = *(const v8s*)psrc;
                #pragma unroll
                for (int e = 0; e < 4; e++)
                    acc[e] = __builtin_amdgcn_mfma_f32_16x16x32_bf16(a[cur][e], bfr, acc[e], 0, 0, 0);
            }
            if (act) {
                #pragma unroll
                for (int e = 0; e < 4; e++) {
                    const int c0 = o * 128 + (eh * 4 + e) * 16 + quad * 4;
                    const size_t ioff = ((size_t)(b * 2 + half_) * 32 + (c0 >> 5)) * 4096
                                      + ((c0 >> 3) & 3) * 1024 + (size_t)(row0 + l16) * 8 + (c0 & 7);
                    v4u lv = *(const v4u*)&vlocI[ioff];
                    v4u u;
                    #pragma unroll
                    for (int r = 0; r < 4; r++)
                        u[r] = f2bf(fmaxf(acc[e][r] + bf2f(lv[r]), 0.f));
                    *(v4u*)&aoI[ioff] = u;
                }
            }
        }
        __builtin_amdgcn_s_setprio(0);
    }
}

// ---------------------------------------------------------------------------
// K6: projection GEMM (3-deep direct core, K=1024) + BN -> out fp32
// XCD swizzle: 384 blocks = 8 XCDs x (8 b x 6 tiles).
// ---------------------------------------------------------------------------
__global__ __launch_bounds__(256) void k_proj(
    const u16* __restrict__ WpI, const u16* __restrict__ aoI,
    const float* __restrict__ TB, float* __restrict__ out)
{
    const int tid = threadIdx.x;
    const int L = blockIdx.x + 2 * (blockIdx.y + 3 * blockIdx.z);
    const int idx = L >> 3;                 // 0..47
    const int b  = (L & 7) * 8 + idx / 6;   // contiguous b-chunk per XCD
    const int r  = idx % 6;
    const int mt = r >> 1, nt = r & 1;
    v4f acc[4][4] = {};
    gemm_direct3<32>(WpI + (size_t)mt * 131072,
                     aoI + ((size_t)b * 2 + nt) * 131072, acc, tid);

    const int lane = tid & 63, w = tid >> 6;
    const int wm = (w & 1) * 64, wn = (w >> 1) * 64;
    const int quad = lane >> 4, l16 = lane & 15;
    #pragma unroll
    for (int i = 0; i < 4; i++) {
        #pragma unroll
        for (int j = 0; j < 4; j++) {
            int p0 = mt * 128 + wm + i * 16 + quad * 4;
            int n  = nt * 128 + wn + j * 16 + l16;
            if (n < N_) {
                v4f s = *(const v4f*)&TB[3072 + p0];
                v4f t = *(const v4f*)&TB[3456 + p0];
                #pragma unroll
                for (int r2 = 0; r2 < 4; r2++)
                    out[((size_t)b * DIM_ + p0 + r2) * N_ + n] = acc[i][j][r2] * s[r2] + t[r2];
            }
        }
    }
}

// ---------------------------------------------------------------------------
extern "C" void kernel_launch(void* const* d_in, const int* in_sizes, int n_in,
                              void* d_out, int out_size, void* d_ws, size_t ws_size,
                              hipStream_t stream)
{
    const float* x    = (const float*)d_in[0];
    const float* wq   = (const float*)d_in[1];
    const float* bq   = (const float*)d_in[2];
    const float* bnq  = (const float*)d_in[3];
    const float* wk   = (const float*)d_in[4];
    const float* bk   = (const float*)d_in[5];
    const float* bnk  = (const float*)d_in[6];
    const float* wv   = (const float*)d_in[7];
    const float* bv   = (const float*)d_in[8];
    const float* bnv  = (const float*)d_in[9];
    const float* wvl  = (const float*)d_in[10];
    const float* bvl  = (const float*)d_in[11];
    const float* bnvl = (const float*)d_in[12];
    const float* th1w = (const float*)d_in[13];
    const float* th1b = (const float*)d_in[14];
    const float* th2w = (const float*)d_in[15];
    const float* th2b = (const float*)d_in[16];
    const float* wp   = (const float*)d_in[17];
    const float* bp   = (const float*)d_in[18];
    const float* bnp  = (const float*)d_in[19];
    const float* ab   = (const float*)d_in[20];
    const int*   bidx = (const int*)d_in[21];
    float* out = (float*)d_out;

    u16* wsb  = (u16*)d_ws;
    u16* WbI  = wsb + WBI_OFF;
    u16* WpI  = wsb + WPI_OFF;
    u16* qI   = wsb + QI_OFF;
    u16* kI   = wsb + KI_OFF;
    u16* vI   = wsb + VI_OFF;
    u16* vlocI = wsb + VLOC_U16;
    u16* xI   = wsb + TAIL_OFF;   // aliased: xI -> aoI (disjoint lifetimes)
    u16* aoI  = wsb + TAIL_OFF;
    float* TB    = (float*)(wsb + TB_OFF);
    float* biasE = (float*)(wsb + BIASE_OFF);

    k_pre<<<dim3(6588), 256, 0, stream>>>(x, wq, wk, wv, wp, ab, th1w, th1b,
                                          bq, bnq, bk, bnk, bv, bnv, bp, bnp, bvl, bnvl,
                                          bidx, xI, WbI, WpI, TB, biasE);
    k_qkv<<<dim3(2, 12, B_), 256, 0, stream>>>(WbI, xI, TB, qI, kI, vI);
    k_dwconv<<<dim3(16, B_), 256, 0, stream>>>(vI, wvl, TB, vlocI);
    k_attn_av<<<dim3(13, B_), 512, 0, stream>>>(qI, kI, vI, th1w, th2w, th2b,
                                                biasE, vlocI, aoI);
    k_proj<<<dim3(2, 3, B_), 256, 0, stream>>>(WpI, aoI, TB, out);
}